// Round 9
// baseline (340.345 us; speedup 1.0000x reference)
//
#include <hip/hip_runtime.h>
#include <hip/hip_bf16.h>
#include <cstdint>

#define D_MODEL  1024
#define D_INNER  2048
#define D_STATE  16
#define DT_RANK  64
#define KERW     4
#define BATCH    2
#define SEQ      1024
#define NTOK     (BATCH * SEQ)
#define CHUNKS   32
#define LOG2C    5
#define LC       (SEQ / CHUNKS)     // 32 steps per chunk

typedef _Float16 h8 __attribute__((ext_vector_type(8)));
typedef _Float16 h4 __attribute__((ext_vector_type(4)));
typedef float    f32x4 __attribute__((ext_vector_type(4)));

__device__ __forceinline__ float siluf(float x) {
    return x / (1.f + __expf(-x));
}

#define GLOAD_LDS16(g, p) __builtin_amdgcn_global_load_lds( \
    (const __attribute__((address_space(1))) void*)(g),      \
    (__attribute__((address_space(3))) void*)(p), 16, 0, 0)

// ---------------------------------------------------------------------------
// fp32 -> fp16 elementwise (vectorized x4)
// ---------------------------------------------------------------------------
__global__ __launch_bounds__(256)
void f32_to_f16_k(const float* __restrict__ in, _Float16* __restrict__ out, int n4)
{
    int i = blockIdx.x * 256 + threadIdx.x;
    if (i >= n4) return;
    float4 v = ((const float4*)in)[i];
    h4 h = { (_Float16)v.x, (_Float16)v.y, (_Float16)v.z, (_Float16)v.w };
    *(h4*)(out + (size_t)i * 4) = h;
}

// ---------------------------------------------------------------------------
// Pack fp32 B[K][NN] row-major -> fp16 Bp[K/8][NN][8]
// ---------------------------------------------------------------------------
template<int NN>
__global__ __launch_bounds__(256)
void pack_b_f16(const float* __restrict__ B, _Float16* __restrict__ Bp, int K)
{
    constexpr int SH = (NN == 4096) ? 12 : 10;
    int gid = blockIdx.x * 256 + threadIdx.x;
    int n  = gid & (NN - 1);
    int kb = gid >> SH;
    h8 v;
    #pragma unroll
    for (int j = 0; j < 8; ++j)
        v[j] = (_Float16)B[(size_t)(kb * 8 + j) * NN + n];
    *(h8*)(Bp + (size_t)gid * 8) = v;
}

// ---------------------------------------------------------------------------
// fp16 MFMA GEMM: C[M,N] = A[M,K] @ B[K,N], fp32 out.
// BM=128, BN=64, BK=32, 4 waves (2x2), 2-stage LDS dbuf, XCD swizzle,
// optional split-K via gridDim.z (partial z writes C + z*M*ldc).
// ---------------------------------------------------------------------------
__device__ __forceinline__ void stage_tiles(
    const _Float16* __restrict__ A, const _Float16* __restrict__ Bp,
    _Float16* as, _Float16* bs, int bm, int bn, int k0, int N, int lda, int tid)
{
    #pragma unroll
    for (int i = 0; i < 2; ++i) {
        int c = i * 256 + tid;
        int row = c & 127, kgc = c >> 7;
        const _Float16* g = A + (size_t)(bm + row) * lda + k0 + kgc * 8;
        GLOAD_LDS16(g, as + (size_t)c * 8);
    }
    {
        int c = tid;
        int col = c & 63, kgc = c >> 6;
        const _Float16* g = Bp + ((size_t)((k0 >> 3) + kgc) * N + bn + col) * 8;
        GLOAD_LDS16(g, bs + (size_t)c * 8);
    }
}

__global__ __launch_bounds__(256)
void gemm_f16_mfma(const _Float16* __restrict__ A, const _Float16* __restrict__ Bp,
                   float* __restrict__ C, int M, int N, int K, int lda, int ldc)
{
    __shared__ alignas(16) _Float16 As[2][4 * 128 * 8];   // 2 x 8 KB
    __shared__ alignas(16) _Float16 Bs[2][4 * 64 * 8];    // 2 x 4 KB

    const int tid = threadIdx.x;
    const int l = tid & 63, w = tid >> 6;
    const int wm = w >> 1, wn = w & 1;          // 2x2 waves, 64x32 each

    const int nwg = gridDim.x;
    const int qch = nwg >> 3;
    const int wg  = ((blockIdx.x & 7) * qch) + (blockIdx.x >> 3);
    const int nbn = N >> 6;
    const int bn  = (wg % nbn) * 64;
    const int bm  = (wg / nbn) * 128;

    const int kslice = K / gridDim.z;
    const int kbeg = blockIdx.z * kslice;
    const int kend = kbeg + kslice;

    f32x4 acc[4][2] = {};
    const int kg = l >> 4, r = l & 15;

    stage_tiles(A, Bp, As[0], Bs[0], bm, bn, kbeg, N, lda, tid);
    __syncthreads();

    int cur = 0;
    for (int k0 = kbeg; k0 < kend; k0 += 32) {
        if (k0 + 32 < kend)
            stage_tiles(A, Bp, As[cur ^ 1], Bs[cur ^ 1], bm, bn, k0 + 32, N, lda, tid);

        h8 a[4], b[2];
        #pragma unroll
        for (int mi = 0; mi < 4; ++mi)
            a[mi] = *(const h8*)(As[cur] + (size_t)(kg * 128 + wm * 64 + mi * 16 + r) * 8);
        #pragma unroll
        for (int ni = 0; ni < 2; ++ni)
            b[ni] = *(const h8*)(Bs[cur] + (size_t)(kg * 64 + wn * 32 + ni * 16 + r) * 8);

        #pragma unroll
        for (int mi = 0; mi < 4; ++mi)
            #pragma unroll
            for (int ni = 0; ni < 2; ++ni)
                acc[mi][ni] = __builtin_amdgcn_mfma_f32_16x16x32_f16(
                    a[mi], b[ni], acc[mi][ni], 0, 0, 0);

        __syncthreads();
        cur ^= 1;
    }

    float* dst = C + (size_t)blockIdx.z * M * ldc;
    const int q = l >> 4;
    #pragma unroll
    for (int mi = 0; mi < 4; ++mi)
        #pragma unroll
        for (int ni = 0; ni < 2; ++ni)
            #pragma unroll
            for (int j = 0; j < 4; ++j)
                dst[(size_t)(bm + wm * 64 + mi * 16 + q * 4 + j) * ldc
                    + (bn + wn * 32 + ni * 16 + r)] = acc[mi][ni][j];
}

// ---------------------------------------------------------------------------
// Generic fp32 GEMM (GEMM3 only): 64x64 tile.
// ---------------------------------------------------------------------------
template<bool BIAS, bool SOFTPLUS>
__global__ __launch_bounds__(256)
void gemm_f32(const float* __restrict__ A, const float* __restrict__ B,
              const float* __restrict__ bias, float* __restrict__ C,
              int M, int N, int K, int lda, int ldb, int ldc)
{
    __shared__ float As[16][68];
    __shared__ float Bs[16][68];
    const int tid = threadIdx.x;
    const int tx = tid & 15, ty = tid >> 4;
    const int bm = blockIdx.y * 64, bn = blockIdx.x * 64;

    float acc[4][4] = {};

    const int ar  = tid >> 2;
    const int ac4 = (tid & 3) << 2;
    const int bkr = tid >> 4;
    const int bc4 = (tid & 15) << 2;

    for (int k0 = 0; k0 < K; k0 += 16) {
        float4 av = make_float4(0.f, 0.f, 0.f, 0.f);
        {
            int row = bm + ar;
            if (row < M)
                av = *(const float4*)(A + (size_t)row * lda + (k0 + ac4));
        }
        As[ac4 + 0][ar] = av.x; As[ac4 + 1][ar] = av.y;
        As[ac4 + 2][ar] = av.z; As[ac4 + 3][ar] = av.w;

        float4 bv = make_float4(0.f, 0.f, 0.f, 0.f);
        {
            int col = bn + bc4;
            const float* bp = B + (size_t)(k0 + bkr) * ldb + col;
            if (col + 3 < N) {
                bv = *(const float4*)bp;
            } else {
                if (col + 0 < N) bv.x = bp[0];
                if (col + 1 < N) bv.y = bp[1];
                if (col + 2 < N) bv.z = bp[2];
                if (col + 3 < N) bv.w = bp[3];
            }
        }
        Bs[bkr][bc4 + 0] = bv.x; Bs[bkr][bc4 + 1] = bv.y;
        Bs[bkr][bc4 + 2] = bv.z; Bs[bkr][bc4 + 3] = bv.w;

        __syncthreads();

        #pragma unroll
        for (int kk = 0; kk < 16; ++kk) {
            float a[4], b[4];
            #pragma unroll
            for (int i = 0; i < 4; ++i) a[i] = As[kk][ty * 4 + i];
            #pragma unroll
            for (int j = 0; j < 4; ++j) b[j] = Bs[kk][tx * 4 + j];
            #pragma unroll
            for (int i = 0; i < 4; ++i)
                #pragma unroll
                for (int j = 0; j < 4; ++j)
                    acc[i][j] = fmaf(a[i], b[j], acc[i][j]);
        }
        __syncthreads();
    }

    #pragma unroll
    for (int i = 0; i < 4; ++i) {
        int row = bm + ty * 4 + i;
        if (row >= M) continue;
        #pragma unroll
        for (int j = 0; j < 4; ++j) {
            int col = bn + tx * 4 + j;
            if (col >= N) continue;
            float v = acc[i][j];
            if (BIAS) v += bias[col];
            if (SOFTPLUS) v = (v > 20.f) ? v : log1pf(__expf(v));
            C[(size_t)row * ldc + col] = v;
        }
    }
}

// ---------------------------------------------------------------------------
// Split-K fp32 GEMM for GEMM2 (M=2048, N=96, K=2048).
// ---------------------------------------------------------------------------
__global__ __launch_bounds__(256)
void gemm_f32_splitk(const float* __restrict__ A, const float* __restrict__ B,
                     float* __restrict__ part,
                     int M, int N, int K, int lda, int ldb, int ldc)
{
    __shared__ float As[16][68];
    __shared__ float Bs[16][68];
    const int tid = threadIdx.x;
    const int tx = tid & 15, ty = tid >> 4;
    const int bm = blockIdx.y * 64, bn = blockIdx.x * 64;
    const int kslice = K / gridDim.z;
    const int kbeg = blockIdx.z * kslice;

    float acc[4][4] = {};

    const int ar  = tid >> 2;
    const int ac4 = (tid & 3) << 2;
    const int bkr = tid >> 4;
    const int bc4 = (tid & 15) << 2;

    for (int k0 = kbeg; k0 < kbeg + kslice; k0 += 16) {
        float4 av;
        {
            int row = bm + ar;
            av = *(const float4*)(A + (size_t)row * lda + (k0 + ac4));
        }
        As[ac4 + 0][ar] = av.x; As[ac4 + 1][ar] = av.y;
        As[ac4 + 2][ar] = av.z; As[ac4 + 3][ar] = av.w;

        float4 bv = make_float4(0.f, 0.f, 0.f, 0.f);
        {
            int col = bn + bc4;
            const float* bp = B + (size_t)(k0 + bkr) * ldb + col;
            if (col + 3 < N) {
                bv = *(const float4*)bp;
            } else {
                if (col + 0 < N) bv.x = bp[0];
                if (col + 1 < N) bv.y = bp[1];
                if (col + 2 < N) bv.z = bp[2];
                if (col + 3 < N) bv.w = bp[3];
            }
        }
        Bs[bkr][bc4 + 0] = bv.x; Bs[bkr][bc4 + 1] = bv.y;
        Bs[bkr][bc4 + 2] = bv.z; Bs[bkr][bc4 + 3] = bv.w;

        __syncthreads();

        #pragma unroll
        for (int kk = 0; kk < 16; ++kk) {
            float a[4], b[4];
            #pragma unroll
            for (int i = 0; i < 4; ++i) a[i] = As[kk][ty * 4 + i];
            #pragma unroll
            for (int j = 0; j < 4; ++j) b[j] = Bs[kk][tx * 4 + j];
            #pragma unroll
            for (int i = 0; i < 4; ++i)
                #pragma unroll
                for (int j = 0; j < 4; ++j)
                    acc[i][j] = fmaf(a[i], b[j], acc[i][j]);
        }
        __syncthreads();
    }

    float* dst = part + (size_t)blockIdx.z * M * ldc;
    #pragma unroll
    for (int i = 0; i < 4; ++i) {
        int row = bm + ty * 4 + i;
        #pragma unroll
        for (int j = 0; j < 4; ++j) {
            int col = bn + tx * 4 + j;
            if (col >= N) continue;
            dst[(size_t)row * ldc + col] = acc[i][j];
        }
    }
}

__global__ __launch_bounds__(256)
void reduce_splitk(const float* __restrict__ part, float* __restrict__ out,
                   int n, int S)
{
    int i = blockIdx.x * 256 + threadIdx.x;
    if (i >= n) return;
    float s = 0.f;
    for (int j = 0; j < S; ++j) s += part[(size_t)j * n + i];
    out[i] = s;
}

// ---------------------------------------------------------------------------
// Depthwise causal conv (K=4) + bias + SiLU.
// ---------------------------------------------------------------------------
__global__ __launch_bounds__(256)
void conv_silu(const float* __restrict__ xz, const float* __restrict__ conv_w,
               const float* __restrict__ conv_b, float* __restrict__ u)
{
    int idx = blockIdx.x * 256 + threadIdx.x;
    if (idx >= NTOK * D_INNER) return;
    int d = idx & (D_INNER - 1);
    int t = idx >> 11;
    int l = t & (SEQ - 1);
    int b = t >> 10;

    float w0 = conv_w[d * 4 + 0], w1 = conv_w[d * 4 + 1];
    float w2 = conv_w[d * 4 + 2], w3 = conv_w[d * 4 + 3];

    const float* base = xz + (size_t)b * SEQ * (2 * D_INNER) + d;
    float acc = conv_b[d];
    if (l >= 3) acc += w0 * base[(size_t)(l - 3) * (2 * D_INNER)];
    if (l >= 2) acc += w1 * base[(size_t)(l - 2) * (2 * D_INNER)];
    if (l >= 1) acc += w2 * base[(size_t)(l - 1) * (2 * D_INNER)];
    acc += w3 * base[(size_t)l * (2 * D_INNER)];

    u[idx] = siluf(acc);
}

// ---------------------------------------------------------------------------
// Chunk-parallel selective scan — one thread per (b,chunk,d), 16 states in
// registers. State buffers laid out [b][c][d][16].
// ---------------------------------------------------------------------------
__global__ __launch_bounds__(256)
void scan_pass1(const float* __restrict__ delta, const float* __restrict__ u,
                const float* __restrict__ xdbl, const float* __restrict__ A_log,
                float* __restrict__ Aprod, float* __restrict__ Hend)
{
    int t = blockIdx.x * 256 + threadIdx.x;     // over B*CHUNKS*D
    if (t >= BATCH * CHUNKS * D_INNER) return;
    int d  = t & (D_INNER - 1);
    int bc = t >> 11;
    int c  = bc & (CHUNKS - 1);
    int b  = bc >> LOG2C;

    float An[16];
    {
        const float4* a4 = (const float4*)(A_log + d * 16);
        #pragma unroll
        for (int q = 0; q < 4; ++q) {
            float4 v = a4[q];
            An[q * 4 + 0] = -__expf(v.x);
            An[q * 4 + 1] = -__expf(v.y);
            An[q * 4 + 2] = -__expf(v.z);
            An[q * 4 + 3] = -__expf(v.w);
        }
    }

    const float* dp = delta + ((size_t)b * SEQ + c * LC) * D_INNER + d;
    const float* up = u     + ((size_t)b * SEQ + c * LC) * D_INNER + d;
    const float* xb = xdbl  + ((size_t)b * SEQ + c * LC) * 96 + DT_RANK;

    float h[16], ap[16];
    #pragma unroll
    for (int n = 0; n < 16; ++n) { h[n] = 0.f; ap[n] = 1.f; }

    #pragma unroll 2
    for (int l = 0; l < LC; ++l) {
        float dt = dp[(size_t)l * D_INNER];
        float ut = up[(size_t)l * D_INNER];
        const float4* b4 = (const float4*)(xb + l * 96);
        float4 B0 = b4[0], B1 = b4[1], B2 = b4[2], B3 = b4[3];
        float Bv[16] = { B0.x, B0.y, B0.z, B0.w, B1.x, B1.y, B1.z, B1.w,
                         B2.x, B2.y, B2.z, B2.w, B3.x, B3.y, B3.z, B3.w };
        float dtu = dt * ut;
        #pragma unroll
        for (int n = 0; n < 16; ++n) {
            float da = __expf(dt * An[n]);
            h[n]  = fmaf(da, h[n], dtu * Bv[n]);
            ap[n] *= da;
        }
    }

    float4* hp = (float4*)(Hend  + (size_t)t * 16);
    float4* pp = (float4*)(Aprod + (size_t)t * 16);
    #pragma unroll
    for (int q = 0; q < 4; ++q) {
        hp[q] = make_float4(h[q*4+0], h[q*4+1], h[q*4+2], h[q*4+3]);
        pp[q] = make_float4(ap[q*4+0], ap[q*4+1], ap[q*4+2], ap[q*4+3]);
    }
}

__global__ __launch_bounds__(256)
void scan_pass2(const float* __restrict__ Aprod, float* __restrict__ HendHin)
{
    int idx = blockIdx.x * 256 + threadIdx.x;      // (b*D + d)*16 + n
    if (idx >= BATCH * D_INNER * D_STATE) return;
    int n = idx & 15;
    int d = (idx >> 4) & (D_INNER - 1);
    int b = idx >> 15;

    float h = 0.f;
    for (int c = 0; c < CHUNKS; ++c) {
        size_t j = ((((size_t)b * CHUNKS + c) * D_INNER) + d) * 16 + n;
        float ap = Aprod[j];
        float he = HendHin[j];
        HendHin[j] = h;            // Hend -> Hin in place (read-before-write)
        h = ap * h + he;
    }
}

// pass 3: replay from Hin + C-proj + D-skip + silu(res) gate; writes fp16 yg
// (row stride 8192 halfs, lives in the dead x-half of the xz buffer).
__global__ __launch_bounds__(256)
void scan_pass3(const float* __restrict__ delta, const float* __restrict__ u,
                const float* __restrict__ xdbl, const float* __restrict__ xz,
                const float* __restrict__ A_log, const float* __restrict__ D_skip,
                const float* __restrict__ Hin, _Float16* __restrict__ ygh)
{
    int t = blockIdx.x * 256 + threadIdx.x;     // over B*CHUNKS*D
    if (t >= BATCH * CHUNKS * D_INNER) return;
    int d  = t & (D_INNER - 1);
    int bc = t >> 11;
    int c  = bc & (CHUNKS - 1);
    int b  = bc >> LOG2C;

    float An[16];
    {
        const float4* a4 = (const float4*)(A_log + d * 16);
        #pragma unroll
        for (int q = 0; q < 4; ++q) {
            float4 v = a4[q];
            An[q * 4 + 0] = -__expf(v.x);
            An[q * 4 + 1] = -__expf(v.y);
            An[q * 4 + 2] = -__expf(v.z);
            An[q * 4 + 3] = -__expf(v.w);
        }
    }
    float Dd = D_skip[d];

    float h[16];
    {
        const float4* h4p = (const float4*)(Hin + (size_t)t * 16);
        #pragma unroll
        for (int q = 0; q < 4; ++q) {
            float4 v = h4p[q];
            h[q * 4 + 0] = v.x; h[q * 4 + 1] = v.y;
            h[q * 4 + 2] = v.z; h[q * 4 + 3] = v.w;
        }
    }

    const float* dp = delta + ((size_t)b * SEQ + c * LC) * D_INNER + d;
    const float* up = u     + ((size_t)b * SEQ + c * LC) * D_INNER + d;
    const float* xb = xdbl  + ((size_t)b * SEQ + c * LC) * 96 + DT_RANK;
    const float* rp = xz    + ((size_t)b * SEQ + c * LC) * (2 * D_INNER) + D_INNER + d;
    _Float16*    yp = ygh   + ((size_t)b * SEQ + c * LC) * 8192 + d;

    #pragma unroll 2
    for (int l = 0; l < LC; ++l) {
        float dt = dp[(size_t)l * D_INNER];
        float ut = up[(size_t)l * D_INNER];
        float res = rp[(size_t)l * (2 * D_INNER)];
        const float4* b4 = (const float4*)(xb + l * 96);
        float4 B0 = b4[0], B1 = b4[1], B2 = b4[2], B3 = b4[3];
        float4 C0 = b4[4], C1 = b4[5], C2 = b4[6], C3 = b4[7];
        float Bv[16] = { B0.x, B0.y, B0.z, B0.w, B1.x, B1.y, B1.z, B1.w,
                         B2.x, B2.y, B2.z, B2.w, B3.x, B3.y, B3.z, B3.w };
        float Cv[16] = { C0.x, C0.y, C0.z, C0.w, C1.x, C1.y, C1.z, C1.w,
                         C2.x, C2.y, C2.z, C2.w, C3.x, C3.y, C3.z, C3.w };
        float dtu = dt * ut;
        float y = 0.f;
        #pragma unroll
        for (int n = 0; n < 16; ++n) {
            float da = __expf(dt * An[n]);
            h[n] = fmaf(da, h[n], dtu * Bv[n]);
            y = fmaf(h[n], Cv[n], y);
        }
        yp[(size_t)l * 8192] = (_Float16)((y + ut * Dd) * siluf(res));
    }
}

// ---------------------------------------------------------------------------
extern "C" void kernel_launch(void* const* d_in, const int* in_sizes, int n_in,
                              void* d_out, int out_size, void* d_ws, size_t ws_size,
                              hipStream_t stream)
{
    const float* H      = (const float*)d_in[0];
    const float* Win    = (const float*)d_in[1];
    const float* convw  = (const float*)d_in[2];
    const float* convb  = (const float*)d_in[3];
    const float* xprojw = (const float*)d_in[4];
    const float* dtw    = (const float*)d_in[5];
    const float* dtb    = (const float*)d_in[6];
    const float* Alog   = (const float*)d_in[7];
    const float* Dskip  = (const float*)d_in[8];
    const float* Wout   = (const float*)d_in[9];
    float* out = (float*)d_out;

    float* ws    = (float*)d_ws;
    float* xz    = ws;                                   // [NTOK,4096] 32MB
    float* u     = xz   + (size_t)NTOK * 4096;           // 16MB
    float* xdbl  = u    + (size_t)NTOK * 2048;           // 0.75MB
    float* delta = xdbl + (size_t)NTOK * 96;             // 16MB
    float* Aprod = delta + (size_t)NTOK * 2048;          // 8MB (CHUNKS=32)
    float* Hend  = Aprod + (size_t)BATCH * CHUNKS * D_INNER * 16;  // 8MB

    // fp16 / fp32 aliases (lifetime-disjoint with their hosts):
    _Float16* Hh    = (_Float16*)delta;                  // dead after GEMM1
    _Float16* Winp  = (_Float16*)delta + 2 * 1024 * 1024;// dead after GEMM1
    float*    part  = delta;                             // GEMM2 partials (12.6MB)
    float*    part4 = delta;                             // GEMM4 partials (2 x 8MB)
    _Float16* ygh   = (_Float16*)xz;                     // stride 8192 (dead x-half)
    _Float16* Woutp = (_Float16*)Aprod;                  // Aprod dead after pass2

    dim3 blk(256);

    // 0a) Hh = fp16(H)
    f32_to_f16_k<<<(NTOK * D_MODEL / 4) / 256, blk, 0, stream>>>(H, Hh, NTOK * D_MODEL / 4);
    // 0b) Winp = pack(fp16(Win))
    pack_b_f16<4096><<<((D_MODEL / 8) * 4096) / 256, blk, 0, stream>>>(Win, Winp, D_MODEL);

    // 1) xz = H @ Win   (MFMA fp16; 1024 wg)
    gemm_f16_mfma<<<dim3((4096 / 64) * (NTOK / 128), 1, 1), blk, 0, stream>>>(
        Hh, Winp, xz, NTOK, 2 * D_INNER, D_MODEL, D_MODEL, 2 * D_INNER);

    // 2) u = silu(depthwise_conv(x) + b)
    conv_silu<<<(NTOK * D_INNER) / 256, blk, 0, stream>>>(xz, convw, convb, u);

    // 3) x_dbl = u @ x_proj_w  — split-K fp32 (grid z=16), then reduce
    gemm_f32_splitk<<<dim3(2, NTOK / 64, 16), blk, 0, stream>>>(
        u, xprojw, part, NTOK, 96, D_INNER, D_INNER, 96, 96);
    reduce_splitk<<<(NTOK * 96 + 255) / 256, blk, 0, stream>>>(
        part, xdbl, NTOK * 96, 16);

    // 4) delta = softplus(x_dbl[:, :64] @ dt_proj_w + dt_proj_b)  (fp32, K=64)
    gemm_f32<true, true><<<dim3(D_INNER / 64, NTOK / 64), blk, 0, stream>>>(
        xdbl, dtw, dtb, delta, NTOK, D_INNER, DT_RANK, 96, D_INNER, D_INNER);

    // 5) chunk-parallel scan (d-parallel, 16 states per thread, CHUNKS=32)
    {
        int nthr = BATCH * CHUNKS * D_INNER;             // 131,072
        scan_pass1<<<nthr / 256, blk, 0, stream>>>(delta, u, xdbl, Alog, Aprod, Hend);
        scan_pass2<<<(BATCH * D_INNER * 16) / 256, blk, 0, stream>>>(Aprod, Hend);
        scan_pass3<<<nthr / 256, blk, 0, stream>>>(delta, u, xdbl, xz, Alog, Dskip,
                                                   Hend /*Hin*/, ygh);
    }

    // 5b) Woutp = pack(fp16(Wout))
    pack_b_f16<1024><<<((D_INNER / 8) * 1024) / 256, blk, 0, stream>>>(Wout, Woutp, D_INNER);

    // 6) out = yg @ Wout   (MFMA fp16; A stride 8192; split-K=2)
    gemm_f16_mfma<<<dim3((1024 / 64) * (NTOK / 128), 1, 2), blk, 0, stream>>>(
        ygh, Woutp, part4, NTOK, D_MODEL, D_INNER, 8192, D_MODEL);
    reduce_splitk<<<(NTOK * D_MODEL) / 256, blk, 0, stream>>>(
        part4, out, NTOK * D_MODEL, 2);
}

// Round 10
// 290.827 us; speedup vs baseline: 1.1703x; 1.1703x over previous
//
#include <hip/hip_runtime.h>
#include <hip/hip_bf16.h>
#include <cstdint>

#define D_MODEL  1024
#define D_INNER  2048
#define D_STATE  16
#define DT_RANK  64
#define KERW     4
#define BATCH    2
#define SEQ      1024
#define NTOK     (BATCH * SEQ)
#define CHUNKS   32
#define LOG2C    5
#define LC       (SEQ / CHUNKS)     // 32 steps per chunk

typedef _Float16 h8 __attribute__((ext_vector_type(8)));
typedef _Float16 h4 __attribute__((ext_vector_type(4)));
typedef float    f32x4 __attribute__((ext_vector_type(4)));

__device__ __forceinline__ float siluf(float x) {
    return x / (1.f + __expf(-x));
}

#define GLOAD_LDS16(g, p) __builtin_amdgcn_global_load_lds( \
    (const __attribute__((address_space(1))) void*)(g),      \
    (__attribute__((address_space(3))) void*)(p), 16, 0, 0)

// ---------------------------------------------------------------------------
// fp32 -> fp16 elementwise (vectorized x4)
// ---------------------------------------------------------------------------
__global__ __launch_bounds__(256)
void f32_to_f16_k(const float* __restrict__ in, _Float16* __restrict__ out, int n4)
{
    int i = blockIdx.x * 256 + threadIdx.x;
    if (i >= n4) return;
    float4 v = ((const float4*)in)[i];
    h4 h = { (_Float16)v.x, (_Float16)v.y, (_Float16)v.z, (_Float16)v.w };
    *(h4*)(out + (size_t)i * 4) = h;
}

// ---------------------------------------------------------------------------
// Pack fp32 B[K][NN] row-major -> fp16 Bp[K/8][NN][8]
// ---------------------------------------------------------------------------
template<int NN>
__global__ __launch_bounds__(256)
void pack_b_f16(const float* __restrict__ B, _Float16* __restrict__ Bp, int K)
{
    constexpr int SH = (NN == 4096) ? 12 : 10;
    int gid = blockIdx.x * 256 + threadIdx.x;
    int n  = gid & (NN - 1);
    int kb = gid >> SH;
    h8 v;
    #pragma unroll
    for (int j = 0; j < 8; ++j)
        v[j] = (_Float16)B[(size_t)(kb * 8 + j) * NN + n];
    *(h8*)(Bp + (size_t)gid * 8) = v;
}

// ---------------------------------------------------------------------------
// fp16 MFMA GEMM: BM=128, BN=64, BK=32, 4 waves, 2-stage LDS dbuf,
// XCD swizzle, optional split-K via gridDim.z.
// ---------------------------------------------------------------------------
__device__ __forceinline__ void stage_tiles(
    const _Float16* __restrict__ A, const _Float16* __restrict__ Bp,
    _Float16* as, _Float16* bs, int bm, int bn, int k0, int N, int lda, int tid)
{
    #pragma unroll
    for (int i = 0; i < 2; ++i) {
        int c = i * 256 + tid;
        int row = c & 127, kgc = c >> 7;
        const _Float16* g = A + (size_t)(bm + row) * lda + k0 + kgc * 8;
        GLOAD_LDS16(g, as + (size_t)c * 8);
    }
    {
        int c = tid;
        int col = c & 63, kgc = c >> 6;
        const _Float16* g = Bp + ((size_t)((k0 >> 3) + kgc) * N + bn + col) * 8;
        GLOAD_LDS16(g, bs + (size_t)c * 8);
    }
}

__global__ __launch_bounds__(256)
void gemm_f16_mfma(const _Float16* __restrict__ A, const _Float16* __restrict__ Bp,
                   float* __restrict__ C, int M, int N, int K, int lda, int ldc)
{
    __shared__ alignas(16) _Float16 As[2][4 * 128 * 8];
    __shared__ alignas(16) _Float16 Bs[2][4 * 64 * 8];

    const int tid = threadIdx.x;
    const int l = tid & 63, w = tid >> 6;
    const int wm = w >> 1, wn = w & 1;

    const int nwg = gridDim.x;
    const int qch = nwg >> 3;
    const int wg  = ((blockIdx.x & 7) * qch) + (blockIdx.x >> 3);
    const int nbn = N >> 6;
    const int bn  = (wg % nbn) * 64;
    const int bm  = (wg / nbn) * 128;

    const int kslice = K / gridDim.z;
    const int kbeg = blockIdx.z * kslice;
    const int kend = kbeg + kslice;

    f32x4 acc[4][2] = {};
    const int kg = l >> 4, r = l & 15;

    stage_tiles(A, Bp, As[0], Bs[0], bm, bn, kbeg, N, lda, tid);
    __syncthreads();

    int cur = 0;
    for (int k0 = kbeg; k0 < kend; k0 += 32) {
        if (k0 + 32 < kend)
            stage_tiles(A, Bp, As[cur ^ 1], Bs[cur ^ 1], bm, bn, k0 + 32, N, lda, tid);

        h8 a[4], b[2];
        #pragma unroll
        for (int mi = 0; mi < 4; ++mi)
            a[mi] = *(const h8*)(As[cur] + (size_t)(kg * 128 + wm * 64 + mi * 16 + r) * 8);
        #pragma unroll
        for (int ni = 0; ni < 2; ++ni)
            b[ni] = *(const h8*)(Bs[cur] + (size_t)(kg * 64 + wn * 32 + ni * 16 + r) * 8);

        #pragma unroll
        for (int mi = 0; mi < 4; ++mi)
            #pragma unroll
            for (int ni = 0; ni < 2; ++ni)
                acc[mi][ni] = __builtin_amdgcn_mfma_f32_16x16x32_f16(
                    a[mi], b[ni], acc[mi][ni], 0, 0, 0);

        __syncthreads();
        cur ^= 1;
    }

    float* dst = C + (size_t)blockIdx.z * M * ldc;
    const int q = l >> 4;
    #pragma unroll
    for (int mi = 0; mi < 4; ++mi)
        #pragma unroll
        for (int ni = 0; ni < 2; ++ni)
            #pragma unroll
            for (int j = 0; j < 4; ++j)
                dst[(size_t)(bm + wm * 64 + mi * 16 + q * 4 + j) * ldc
                    + (bn + wn * 32 + ni * 16 + r)] = acc[mi][ni][j];
}

// ---------------------------------------------------------------------------
// Generic fp32 GEMM (GEMM3 only): 64x64 tile.
// ---------------------------------------------------------------------------
template<bool BIAS, bool SOFTPLUS>
__global__ __launch_bounds__(256)
void gemm_f32(const float* __restrict__ A, const float* __restrict__ B,
              const float* __restrict__ bias, float* __restrict__ C,
              int M, int N, int K, int lda, int ldb, int ldc)
{
    __shared__ float As[16][68];
    __shared__ float Bs[16][68];
    const int tid = threadIdx.x;
    const int tx = tid & 15, ty = tid >> 4;
    const int bm = blockIdx.y * 64, bn = blockIdx.x * 64;

    float acc[4][4] = {};

    const int ar  = tid >> 2;
    const int ac4 = (tid & 3) << 2;
    const int bkr = tid >> 4;
    const int bc4 = (tid & 15) << 2;

    for (int k0 = 0; k0 < K; k0 += 16) {
        float4 av = make_float4(0.f, 0.f, 0.f, 0.f);
        {
            int row = bm + ar;
            if (row < M)
                av = *(const float4*)(A + (size_t)row * lda + (k0 + ac4));
        }
        As[ac4 + 0][ar] = av.x; As[ac4 + 1][ar] = av.y;
        As[ac4 + 2][ar] = av.z; As[ac4 + 3][ar] = av.w;

        float4 bv = make_float4(0.f, 0.f, 0.f, 0.f);
        {
            int col = bn + bc4;
            const float* bp = B + (size_t)(k0 + bkr) * ldb + col;
            if (col + 3 < N) {
                bv = *(const float4*)bp;
            } else {
                if (col + 0 < N) bv.x = bp[0];
                if (col + 1 < N) bv.y = bp[1];
                if (col + 2 < N) bv.z = bp[2];
                if (col + 3 < N) bv.w = bp[3];
            }
        }
        Bs[bkr][bc4 + 0] = bv.x; Bs[bkr][bc4 + 1] = bv.y;
        Bs[bkr][bc4 + 2] = bv.z; Bs[bkr][bc4 + 3] = bv.w;

        __syncthreads();

        #pragma unroll
        for (int kk = 0; kk < 16; ++kk) {
            float a[4], b[4];
            #pragma unroll
            for (int i = 0; i < 4; ++i) a[i] = As[kk][ty * 4 + i];
            #pragma unroll
            for (int j = 0; j < 4; ++j) b[j] = Bs[kk][tx * 4 + j];
            #pragma unroll
            for (int i = 0; i < 4; ++i)
                #pragma unroll
                for (int j = 0; j < 4; ++j)
                    acc[i][j] = fmaf(a[i], b[j], acc[i][j]);
        }
        __syncthreads();
    }

    #pragma unroll
    for (int i = 0; i < 4; ++i) {
        int row = bm + ty * 4 + i;
        if (row >= M) continue;
        #pragma unroll
        for (int j = 0; j < 4; ++j) {
            int col = bn + tx * 4 + j;
            if (col >= N) continue;
            float v = acc[i][j];
            if (BIAS) v += bias[col];
            if (SOFTPLUS) v = (v > 20.f) ? v : log1pf(__expf(v));
            C[(size_t)row * ldc + col] = v;
        }
    }
}

// ---------------------------------------------------------------------------
// Split-K fp32 GEMM for GEMM2 (M=2048, N=96, K=2048).
// ---------------------------------------------------------------------------
__global__ __launch_bounds__(256)
void gemm_f32_splitk(const float* __restrict__ A, const float* __restrict__ B,
                     float* __restrict__ part,
                     int M, int N, int K, int lda, int ldb, int ldc)
{
    __shared__ float As[16][68];
    __shared__ float Bs[16][68];
    const int tid = threadIdx.x;
    const int tx = tid & 15, ty = tid >> 4;
    const int bm = blockIdx.y * 64, bn = blockIdx.x * 64;
    const int kslice = K / gridDim.z;
    const int kbeg = blockIdx.z * kslice;

    float acc[4][4] = {};

    const int ar  = tid >> 2;
    const int ac4 = (tid & 3) << 2;
    const int bkr = tid >> 4;
    const int bc4 = (tid & 15) << 2;

    for (int k0 = kbeg; k0 < kbeg + kslice; k0 += 16) {
        float4 av;
        {
            int row = bm + ar;
            av = *(const float4*)(A + (size_t)row * lda + (k0 + ac4));
        }
        As[ac4 + 0][ar] = av.x; As[ac4 + 1][ar] = av.y;
        As[ac4 + 2][ar] = av.z; As[ac4 + 3][ar] = av.w;

        float4 bv = make_float4(0.f, 0.f, 0.f, 0.f);
        {
            int col = bn + bc4;
            const float* bp = B + (size_t)(k0 + bkr) * ldb + col;
            if (col + 3 < N) {
                bv = *(const float4*)bp;
            } else {
                if (col + 0 < N) bv.x = bp[0];
                if (col + 1 < N) bv.y = bp[1];
                if (col + 2 < N) bv.z = bp[2];
                if (col + 3 < N) bv.w = bp[3];
            }
        }
        Bs[bkr][bc4 + 0] = bv.x; Bs[bkr][bc4 + 1] = bv.y;
        Bs[bkr][bc4 + 2] = bv.z; Bs[bkr][bc4 + 3] = bv.w;

        __syncthreads();

        #pragma unroll
        for (int kk = 0; kk < 16; ++kk) {
            float a[4], b[4];
            #pragma unroll
            for (int i = 0; i < 4; ++i) a[i] = As[kk][ty * 4 + i];
            #pragma unroll
            for (int j = 0; j < 4; ++j) b[j] = Bs[kk][tx * 4 + j];
            #pragma unroll
            for (int i = 0; i < 4; ++i)
                #pragma unroll
                for (int j = 0; j < 4; ++j)
                    acc[i][j] = fmaf(a[i], b[j], acc[i][j]);
        }
        __syncthreads();
    }

    float* dst = part + (size_t)blockIdx.z * M * ldc;
    #pragma unroll
    for (int i = 0; i < 4; ++i) {
        int row = bm + ty * 4 + i;
        #pragma unroll
        for (int j = 0; j < 4; ++j) {
            int col = bn + tx * 4 + j;
            if (col >= N) continue;
            dst[(size_t)row * ldc + col] = acc[i][j];
        }
    }
}

__global__ __launch_bounds__(256)
void reduce_splitk(const float* __restrict__ part, float* __restrict__ out,
                   int n, int S)
{
    int i = blockIdx.x * 256 + threadIdx.x;
    if (i >= n) return;
    float s = 0.f;
    for (int j = 0; j < S; ++j) s += part[(size_t)j * n + i];
    out[i] = s;
}

// ---------------------------------------------------------------------------
// Depthwise causal conv (K=4) + bias + SiLU.
// ---------------------------------------------------------------------------
__global__ __launch_bounds__(256)
void conv_silu(const float* __restrict__ xz, const float* __restrict__ conv_w,
               const float* __restrict__ conv_b, float* __restrict__ u)
{
    int idx = blockIdx.x * 256 + threadIdx.x;
    if (idx >= NTOK * D_INNER) return;
    int d = idx & (D_INNER - 1);
    int t = idx >> 11;
    int l = t & (SEQ - 1);
    int b = t >> 10;

    float w0 = conv_w[d * 4 + 0], w1 = conv_w[d * 4 + 1];
    float w2 = conv_w[d * 4 + 2], w3 = conv_w[d * 4 + 3];

    const float* base = xz + (size_t)b * SEQ * (2 * D_INNER) + d;
    float acc = conv_b[d];
    if (l >= 3) acc += w0 * base[(size_t)(l - 3) * (2 * D_INNER)];
    if (l >= 2) acc += w1 * base[(size_t)(l - 2) * (2 * D_INNER)];
    if (l >= 1) acc += w2 * base[(size_t)(l - 1) * (2 * D_INNER)];
    acc += w3 * base[(size_t)l * (2 * D_INNER)];

    u[idx] = siluf(acc);
}

// ---------------------------------------------------------------------------
// Chunk-parallel selective scan — 2 threads per (b,chunk,d), 8 states each
// (half-wave split: lanes 0-31 = n 0..7 of 32 consecutive d, lanes 32-63 =
// n 8..15 of the same d). Explicit 1-deep register pipeline: step l+1's
// loads issue before step l's exp/fma chain. State layout [b][c][d][16].
// ---------------------------------------------------------------------------
__global__ __launch_bounds__(256)
void scan_pass1(const float* __restrict__ delta, const float* __restrict__ u,
                const float* __restrict__ xdbl, const float* __restrict__ A_log,
                float* __restrict__ Aprod, float* __restrict__ Hend)
{
    int gid = blockIdx.x * 256 + threadIdx.x;   // over B*CHUNKS*D*2
    if (gid >= BATCH * CHUNKS * D_INNER * 2) return;
    int lane = gid & 63;
    int wv   = gid >> 6;
    int dsub = lane & 31, nh = lane >> 5;
    int dblk = wv & 63;                          // D_INNER/32
    int c    = (wv >> 6) & (CHUNKS - 1);
    int b    = wv >> (6 + LOG2C);
    int d    = dblk * 32 + dsub;

    float An[8];
    {
        const float4* a4 = (const float4*)(A_log + d * 16 + nh * 8);
        #pragma unroll
        for (int q = 0; q < 2; ++q) {
            float4 v = a4[q];
            An[q * 4 + 0] = -__expf(v.x);
            An[q * 4 + 1] = -__expf(v.y);
            An[q * 4 + 2] = -__expf(v.z);
            An[q * 4 + 3] = -__expf(v.w);
        }
    }

    const float* dp = delta + ((size_t)b * SEQ + c * LC) * D_INNER + d;
    const float* up = u     + ((size_t)b * SEQ + c * LC) * D_INNER + d;
    const float* xb = xdbl  + ((size_t)b * SEQ + c * LC) * 96 + DT_RANK + nh * 8;

    float h[8], ap[8];
    #pragma unroll
    for (int n = 0; n < 8; ++n) { h[n] = 0.f; ap[n] = 1.f; }

    // pipeline prologue
    float  dt = dp[0], ut = up[0];
    float4 Bq0 = *(const float4*)(xb);
    float4 Bq1 = *(const float4*)(xb + 4);

    for (int l = 0; l < LC - 1; ++l) {
        // issue next step's loads before this step's compute
        float  dt_n = dp[(size_t)(l + 1) * D_INNER];
        float  ut_n = up[(size_t)(l + 1) * D_INNER];
        float4 B0n  = *(const float4*)(xb + (l + 1) * 96);
        float4 B1n  = *(const float4*)(xb + (l + 1) * 96 + 4);

        float Bv[8] = { Bq0.x, Bq0.y, Bq0.z, Bq0.w, Bq1.x, Bq1.y, Bq1.z, Bq1.w };
        float dtu = dt * ut;
        #pragma unroll
        for (int n = 0; n < 8; ++n) {
            float da = __expf(dt * An[n]);
            h[n]  = fmaf(da, h[n], dtu * Bv[n]);
            ap[n] *= da;
        }
        dt = dt_n; ut = ut_n; Bq0 = B0n; Bq1 = B1n;
    }
    {   // final step
        float Bv[8] = { Bq0.x, Bq0.y, Bq0.z, Bq0.w, Bq1.x, Bq1.y, Bq1.z, Bq1.w };
        float dtu = dt * ut;
        #pragma unroll
        for (int n = 0; n < 8; ++n) {
            float da = __expf(dt * An[n]);
            h[n]  = fmaf(da, h[n], dtu * Bv[n]);
            ap[n] *= da;
        }
    }

    size_t off = ((((size_t)b * CHUNKS + c) * D_INNER) + d) * 16 + nh * 8;
    *(float4*)(Hend  + off)     = make_float4(h[0], h[1], h[2], h[3]);
    *(float4*)(Hend  + off + 4) = make_float4(h[4], h[5], h[6], h[7]);
    *(float4*)(Aprod + off)     = make_float4(ap[0], ap[1], ap[2], ap[3]);
    *(float4*)(Aprod + off + 4) = make_float4(ap[4], ap[5], ap[6], ap[7]);
}

__global__ __launch_bounds__(256)
void scan_pass2(const float* __restrict__ Aprod, float* __restrict__ HendHin)
{
    int idx = blockIdx.x * 256 + threadIdx.x;      // (b*D + d)*16 + n
    if (idx >= BATCH * D_INNER * D_STATE) return;
    int n = idx & 15;
    int d = (idx >> 4) & (D_INNER - 1);
    int b = idx >> 15;

    float h = 0.f;
    for (int c = 0; c < CHUNKS; ++c) {
        size_t j = ((((size_t)b * CHUNKS + c) * D_INNER) + d) * 16 + n;
        float ap = Aprod[j];
        float he = HendHin[j];
        HendHin[j] = h;            // Hend -> Hin in place (read-before-write)
        h = ap * h + he;
    }
}

// pass 3: replay from Hin + C-proj + D-skip + silu(res) gate; fp16 yg out
// (row stride 8192 halfs, dead x-half of xz). Half-wave n-split + pipeline;
// y-reduction = one __shfl_xor across the half-wave boundary.
__global__ __launch_bounds__(256)
void scan_pass3(const float* __restrict__ delta, const float* __restrict__ u,
                const float* __restrict__ xdbl, const float* __restrict__ xz,
                const float* __restrict__ A_log, const float* __restrict__ D_skip,
                const float* __restrict__ Hin, _Float16* __restrict__ ygh)
{
    int gid = blockIdx.x * 256 + threadIdx.x;   // over B*CHUNKS*D*2
    if (gid >= BATCH * CHUNKS * D_INNER * 2) return;
    int lane = gid & 63;
    int wv   = gid >> 6;
    int dsub = lane & 31, nh = lane >> 5;
    int dblk = wv & 63;
    int c    = (wv >> 6) & (CHUNKS - 1);
    int b    = wv >> (6 + LOG2C);
    int d    = dblk * 32 + dsub;

    float An[8];
    {
        const float4* a4 = (const float4*)(A_log + d * 16 + nh * 8);
        #pragma unroll
        for (int q = 0; q < 2; ++q) {
            float4 v = a4[q];
            An[q * 4 + 0] = -__expf(v.x);
            An[q * 4 + 1] = -__expf(v.y);
            An[q * 4 + 2] = -__expf(v.z);
            An[q * 4 + 3] = -__expf(v.w);
        }
    }
    float Dd = D_skip[d];

    float h[8];
    {
        size_t off = ((((size_t)b * CHUNKS + c) * D_INNER) + d) * 16 + nh * 8;
        float4 v0 = *(const float4*)(Hin + off);
        float4 v1 = *(const float4*)(Hin + off + 4);
        h[0] = v0.x; h[1] = v0.y; h[2] = v0.z; h[3] = v0.w;
        h[4] = v1.x; h[5] = v1.y; h[6] = v1.z; h[7] = v1.w;
    }

    const float* dp = delta + ((size_t)b * SEQ + c * LC) * D_INNER + d;
    const float* up = u     + ((size_t)b * SEQ + c * LC) * D_INNER + d;
    const float* xb = xdbl  + ((size_t)b * SEQ + c * LC) * 96 + DT_RANK + nh * 8;
    const float* rp = xz    + ((size_t)b * SEQ + c * LC) * (2 * D_INNER) + D_INNER + d;
    _Float16*    yp = ygh   + ((size_t)b * SEQ + c * LC) * 8192 + d;

    // pipeline prologue
    float  dt = dp[0], ut = up[0], res = rp[0];
    float4 Bq0 = *(const float4*)(xb);
    float4 Bq1 = *(const float4*)(xb + 4);
    float4 Cq0 = *(const float4*)(xb + 16);
    float4 Cq1 = *(const float4*)(xb + 20);

    for (int l = 0; l < LC; ++l) {
        float dt_n, ut_n, res_n;
        float4 B0n, B1n, C0n, C1n;
        if (l + 1 < LC) {
            dt_n  = dp[(size_t)(l + 1) * D_INNER];
            ut_n  = up[(size_t)(l + 1) * D_INNER];
            res_n = rp[(size_t)(l + 1) * (2 * D_INNER)];
            B0n = *(const float4*)(xb + (l + 1) * 96);
            B1n = *(const float4*)(xb + (l + 1) * 96 + 4);
            C0n = *(const float4*)(xb + (l + 1) * 96 + 16);
            C1n = *(const float4*)(xb + (l + 1) * 96 + 20);
        }

        float Bv[8] = { Bq0.x, Bq0.y, Bq0.z, Bq0.w, Bq1.x, Bq1.y, Bq1.z, Bq1.w };
        float Cv[8] = { Cq0.x, Cq0.y, Cq0.z, Cq0.w, Cq1.x, Cq1.y, Cq1.z, Cq1.w };
        float dtu = dt * ut;
        float y = 0.f;
        #pragma unroll
        for (int n = 0; n < 8; ++n) {
            float da = __expf(dt * An[n]);
            h[n] = fmaf(da, h[n], dtu * Bv[n]);
            y = fmaf(h[n], Cv[n], y);
        }
        y += __shfl_xor(y, 32, 64);              // combine the two n-halves
        if (nh == 0)
            yp[(size_t)l * 8192] = (_Float16)((y + ut * Dd) * siluf(res));

        dt = dt_n; ut = ut_n; res = res_n;
        Bq0 = B0n; Bq1 = B1n; Cq0 = C0n; Cq1 = C1n;
    }
}

// ---------------------------------------------------------------------------
extern "C" void kernel_launch(void* const* d_in, const int* in_sizes, int n_in,
                              void* d_out, int out_size, void* d_ws, size_t ws_size,
                              hipStream_t stream)
{
    const float* H      = (const float*)d_in[0];
    const float* Win    = (const float*)d_in[1];
    const float* convw  = (const float*)d_in[2];
    const float* convb  = (const float*)d_in[3];
    const float* xprojw = (const float*)d_in[4];
    const float* dtw    = (const float*)d_in[5];
    const float* dtb    = (const float*)d_in[6];
    const float* Alog   = (const float*)d_in[7];
    const float* Dskip  = (const float*)d_in[8];
    const float* Wout   = (const float*)d_in[9];
    float* out = (float*)d_out;

    float* ws    = (float*)d_ws;
    float* xz    = ws;                                   // [NTOK,4096] 32MB
    float* u     = xz   + (size_t)NTOK * 4096;           // 16MB
    float* xdbl  = u    + (size_t)NTOK * 2048;           // 0.75MB
    float* delta = xdbl + (size_t)NTOK * 96;             // 16MB
    float* Aprod = delta + (size_t)NTOK * 2048;          // 8MB (CHUNKS=32)
    float* Hend  = Aprod + (size_t)BATCH * CHUNKS * D_INNER * 16;  // 8MB

    // aliases (lifetime-disjoint):
    _Float16* Hh    = (_Float16*)delta;                  // dead after GEMM1
    _Float16* Winp  = (_Float16*)delta + 2 * 1024 * 1024;// dead after GEMM1
    float*    part  = delta;                             // GEMM2 partials
    float*    part4 = delta;                             // GEMM4 partials (2x8MB)
    _Float16* ygh   = (_Float16*)xz;                     // stride 8192 (dead x-half)
    _Float16* Woutp = (_Float16*)Aprod;                  // Aprod dead after pass2

    dim3 blk(256);

    // 0a) Hh = fp16(H)
    f32_to_f16_k<<<(NTOK * D_MODEL / 4) / 256, blk, 0, stream>>>(H, Hh, NTOK * D_MODEL / 4);
    // 0b) Winp = pack(fp16(Win))
    pack_b_f16<4096><<<((D_MODEL / 8) * 4096) / 256, blk, 0, stream>>>(Win, Winp, D_MODEL);

    // 1) xz = H @ Win   (MFMA fp16; 1024 wg)
    gemm_f16_mfma<<<dim3((4096 / 64) * (NTOK / 128), 1, 1), blk, 0, stream>>>(
        Hh, Winp, xz, NTOK, 2 * D_INNER, D_MODEL, D_MODEL, 2 * D_INNER);

    // 2) u = silu(depthwise_conv(x) + b)
    conv_silu<<<(NTOK * D_INNER) / 256, blk, 0, stream>>>(xz, convw, convb, u);

    // 3) x_dbl = u @ x_proj_w  — split-K fp32 (z=16), then reduce
    gemm_f32_splitk<<<dim3(2, NTOK / 64, 16), blk, 0, stream>>>(
        u, xprojw, part, NTOK, 96, D_INNER, D_INNER, 96, 96);
    reduce_splitk<<<(NTOK * 96 + 255) / 256, blk, 0, stream>>>(
        part, xdbl, NTOK * 96, 16);

    // 4) delta = softplus(x_dbl[:, :64] @ dt_proj_w + dt_proj_b)
    gemm_f32<true, true><<<dim3(D_INNER / 64, NTOK / 64), blk, 0, stream>>>(
        xdbl, dtw, dtb, delta, NTOK, D_INNER, DT_RANK, 96, D_INNER, D_INNER);

    // 5) chunk-parallel scan (half-wave n-split, register pipeline)
    {
        int nthr2 = BATCH * CHUNKS * D_INNER * 2;        // 262,144
        scan_pass1<<<nthr2 / 256, blk, 0, stream>>>(delta, u, xdbl, Alog, Aprod, Hend);
        scan_pass2<<<(BATCH * D_INNER * 16) / 256, blk, 0, stream>>>(Aprod, Hend);
        scan_pass3<<<nthr2 / 256, blk, 0, stream>>>(delta, u, xdbl, xz, Alog, Dskip,
                                                    Hend /*Hin*/, ygh);
    }

    // 5b) Woutp = pack(fp16(Wout))
    pack_b_f16<1024><<<((D_INNER / 8) * 1024) / 256, blk, 0, stream>>>(Wout, Woutp, D_INNER);

    // 6) out = yg @ Wout   (MFMA fp16; A stride 8192; split-K=2)
    gemm_f16_mfma<<<dim3((1024 / 64) * (NTOK / 128), 1, 2), blk, 0, stream>>>(
        ygh, Woutp, part4, NTOK, D_MODEL, D_INNER, 8192, D_MODEL);
    reduce_splitk<<<(NTOK * D_MODEL) / 256, blk, 0, stream>>>(
        part4, out, NTOK * D_MODEL, 2);
}

// Round 11
// 290.448 us; speedup vs baseline: 1.1718x; 1.0013x over previous
//
#include <hip/hip_runtime.h>
#include <hip/hip_bf16.h>
#include <cstdint>

#define D_MODEL  1024
#define D_INNER  2048
#define D_STATE  16
#define DT_RANK  64
#define KERW     4
#define BATCH    2
#define SEQ      1024
#define NTOK     (BATCH * SEQ)
#define CHUNKS   32
#define LOG2C    5
#define LC       (SEQ / CHUNKS)     // 32 steps per chunk

typedef _Float16 h8 __attribute__((ext_vector_type(8)));
typedef _Float16 h4 __attribute__((ext_vector_type(4)));
typedef float    f32x4 __attribute__((ext_vector_type(4)));

__device__ __forceinline__ float siluf(float x) {
    return x / (1.f + __expf(-x));
}

#define GLOAD_LDS16(g, p) __builtin_amdgcn_global_load_lds( \
    (const __attribute__((address_space(1))) void*)(g),      \
    (__attribute__((address_space(3))) void*)(p), 16, 0, 0)

// ---------------------------------------------------------------------------
// Prep (one dispatch): H->fp16 ; pack Win [1024,4096] -> [128][4096][8] ;
// pack Wout [2048,1024] -> [256][1024][8].
// ---------------------------------------------------------------------------
__global__ __launch_bounds__(256)
void prep_kernel(const float* __restrict__ H, const float* __restrict__ Win,
                 const float* __restrict__ Wout, _Float16* __restrict__ Hh,
                 _Float16* __restrict__ Winp, _Float16* __restrict__ Woutp)
{
    int bid = blockIdx.x;
    int tid = threadIdx.x;
    if (bid < 2048) {                       // H -> fp16 (x4)
        int i = bid * 256 + tid;            // over NTOK*1024/4
        float4 v = ((const float4*)H)[i];
        h4 h = { (_Float16)v.x, (_Float16)v.y, (_Float16)v.z, (_Float16)v.w };
        *(h4*)(Hh + (size_t)i * 4) = h;
    } else if (bid < 4096) {                // pack Win (NN=4096)
        int gid = (bid - 2048) * 256 + tid;
        int n  = gid & 4095;
        int kb = gid >> 12;
        h8 v;
        #pragma unroll
        for (int j = 0; j < 8; ++j)
            v[j] = (_Float16)Win[(size_t)(kb * 8 + j) * 4096 + n];
        *(h8*)(Winp + (size_t)gid * 8) = v;
    } else {                                // pack Wout (NN=1024)
        int gid = (bid - 4096) * 256 + tid;
        int n  = gid & 1023;
        int kb = gid >> 10;
        h8 v;
        #pragma unroll
        for (int j = 0; j < 8; ++j)
            v[j] = (_Float16)Wout[(size_t)(kb * 8 + j) * 1024 + n];
        *(h8*)(Woutp + (size_t)gid * 8) = v;
    }
}

// ---------------------------------------------------------------------------
// fp16 MFMA GEMM: BM=128, BN=64, BK=32, 4 waves, 2-stage LDS dbuf,
// XCD swizzle, optional split-K via gridDim.z.
// ---------------------------------------------------------------------------
__device__ __forceinline__ void stage_tiles(
    const _Float16* __restrict__ A, const _Float16* __restrict__ Bp,
    _Float16* as, _Float16* bs, int bm, int bn, int k0, int N, int lda, int tid)
{
    #pragma unroll
    for (int i = 0; i < 2; ++i) {
        int c = i * 256 + tid;
        int row = c & 127, kgc = c >> 7;
        const _Float16* g = A + (size_t)(bm + row) * lda + k0 + kgc * 8;
        GLOAD_LDS16(g, as + (size_t)c * 8);
    }
    {
        int c = tid;
        int col = c & 63, kgc = c >> 6;
        const _Float16* g = Bp + ((size_t)((k0 >> 3) + kgc) * N + bn + col) * 8;
        GLOAD_LDS16(g, bs + (size_t)c * 8);
    }
}

__global__ __launch_bounds__(256)
void gemm_f16_mfma(const _Float16* __restrict__ A, const _Float16* __restrict__ Bp,
                   float* __restrict__ C, int M, int N, int K, int lda, int ldc)
{
    __shared__ alignas(16) _Float16 As[2][4 * 128 * 8];
    __shared__ alignas(16) _Float16 Bs[2][4 * 64 * 8];

    const int tid = threadIdx.x;
    const int l = tid & 63, w = tid >> 6;
    const int wm = w >> 1, wn = w & 1;

    const int nwg = gridDim.x;
    const int qch = nwg >> 3;
    const int wg  = ((blockIdx.x & 7) * qch) + (blockIdx.x >> 3);
    const int nbn = N >> 6;
    const int bn  = (wg % nbn) * 64;
    const int bm  = (wg / nbn) * 128;

    const int kslice = K / gridDim.z;
    const int kbeg = blockIdx.z * kslice;
    const int kend = kbeg + kslice;

    f32x4 acc[4][2] = {};
    const int kg = l >> 4, r = l & 15;

    stage_tiles(A, Bp, As[0], Bs[0], bm, bn, kbeg, N, lda, tid);
    __syncthreads();

    int cur = 0;
    for (int k0 = kbeg; k0 < kend; k0 += 32) {
        if (k0 + 32 < kend)
            stage_tiles(A, Bp, As[cur ^ 1], Bs[cur ^ 1], bm, bn, k0 + 32, N, lda, tid);

        h8 a[4], b[2];
        #pragma unroll
        for (int mi = 0; mi < 4; ++mi)
            a[mi] = *(const h8*)(As[cur] + (size_t)(kg * 128 + wm * 64 + mi * 16 + r) * 8);
        #pragma unroll
        for (int ni = 0; ni < 2; ++ni)
            b[ni] = *(const h8*)(Bs[cur] + (size_t)(kg * 64 + wn * 32 + ni * 16 + r) * 8);

        #pragma unroll
        for (int mi = 0; mi < 4; ++mi)
            #pragma unroll
            for (int ni = 0; ni < 2; ++ni)
                acc[mi][ni] = __builtin_amdgcn_mfma_f32_16x16x32_f16(
                    a[mi], b[ni], acc[mi][ni], 0, 0, 0);

        __syncthreads();
        cur ^= 1;
    }

    float* dst = C + (size_t)blockIdx.z * M * ldc;
    const int q = l >> 4;
    #pragma unroll
    for (int mi = 0; mi < 4; ++mi)
        #pragma unroll
        for (int ni = 0; ni < 2; ++ni)
            #pragma unroll
            for (int j = 0; j < 4; ++j)
                dst[(size_t)(bm + wm * 64 + mi * 16 + q * 4 + j) * ldc
                    + (bn + wn * 32 + ni * 16 + r)] = acc[mi][ni][j];
}

// ---------------------------------------------------------------------------
// Generic fp32 GEMM (GEMM3 only): 64x64 tile.
// ---------------------------------------------------------------------------
template<bool BIAS, bool SOFTPLUS>
__global__ __launch_bounds__(256)
void gemm_f32(const float* __restrict__ A, const float* __restrict__ B,
              const float* __restrict__ bias, float* __restrict__ C,
              int M, int N, int K, int lda, int ldb, int ldc)
{
    __shared__ float As[16][68];
    __shared__ float Bs[16][68];
    const int tid = threadIdx.x;
    const int tx = tid & 15, ty = tid >> 4;
    const int bm = blockIdx.y * 64, bn = blockIdx.x * 64;

    float acc[4][4] = {};

    const int ar  = tid >> 2;
    const int ac4 = (tid & 3) << 2;
    const int bkr = tid >> 4;
    const int bc4 = (tid & 15) << 2;

    for (int k0 = 0; k0 < K; k0 += 16) {
        float4 av = make_float4(0.f, 0.f, 0.f, 0.f);
        {
            int row = bm + ar;
            if (row < M)
                av = *(const float4*)(A + (size_t)row * lda + (k0 + ac4));
        }
        As[ac4 + 0][ar] = av.x; As[ac4 + 1][ar] = av.y;
        As[ac4 + 2][ar] = av.z; As[ac4 + 3][ar] = av.w;

        float4 bv = make_float4(0.f, 0.f, 0.f, 0.f);
        {
            int col = bn + bc4;
            const float* bp = B + (size_t)(k0 + bkr) * ldb + col;
            if (col + 3 < N) {
                bv = *(const float4*)bp;
            } else {
                if (col + 0 < N) bv.x = bp[0];
                if (col + 1 < N) bv.y = bp[1];
                if (col + 2 < N) bv.z = bp[2];
                if (col + 3 < N) bv.w = bp[3];
            }
        }
        Bs[bkr][bc4 + 0] = bv.x; Bs[bkr][bc4 + 1] = bv.y;
        Bs[bkr][bc4 + 2] = bv.z; Bs[bkr][bc4 + 3] = bv.w;

        __syncthreads();

        #pragma unroll
        for (int kk = 0; kk < 16; ++kk) {
            float a[4], b[4];
            #pragma unroll
            for (int i = 0; i < 4; ++i) a[i] = As[kk][ty * 4 + i];
            #pragma unroll
            for (int j = 0; j < 4; ++j) b[j] = Bs[kk][tx * 4 + j];
            #pragma unroll
            for (int i = 0; i < 4; ++i)
                #pragma unroll
                for (int j = 0; j < 4; ++j)
                    acc[i][j] = fmaf(a[i], b[j], acc[i][j]);
        }
        __syncthreads();
    }

    #pragma unroll
    for (int i = 0; i < 4; ++i) {
        int row = bm + ty * 4 + i;
        if (row >= M) continue;
        #pragma unroll
        for (int j = 0; j < 4; ++j) {
            int col = bn + tx * 4 + j;
            if (col >= N) continue;
            float v = acc[i][j];
            if (BIAS) v += bias[col];
            if (SOFTPLUS) v = (v > 20.f) ? v : log1pf(__expf(v));
            C[(size_t)row * ldc + col] = v;
        }
    }
}

// ---------------------------------------------------------------------------
// GEMM2 with FUSED depthwise conv + SiLU on the A operand:
// x_dbl = silu(conv(x)+cb) @ xprojw.  A is computed on the fly from xz's x
// half (row stride 4096). M=2048, N=96, K=2048, split-K via gridDim.z.
// ---------------------------------------------------------------------------
__global__ __launch_bounds__(256)
void gemm2_conv_splitk(const float* __restrict__ xz, const float* __restrict__ convw,
                       const float* __restrict__ convb, const float* __restrict__ B,
                       float* __restrict__ part)
{
    __shared__ float As[16][68];
    __shared__ float Bs[16][68];
    const int tid = threadIdx.x;
    const int tx = tid & 15, ty = tid >> 4;
    const int bm = blockIdx.y * 64, bn = blockIdx.x * 64;
    const int kslice = D_INNER / gridDim.z;
    const int kbeg = blockIdx.z * kslice;

    float acc[4][4] = {};

    const int ar  = tid >> 2;
    const int ac4 = (tid & 3) << 2;
    const int bkr = tid >> 4;
    const int bc4 = (tid & 15) << 2;

    for (int k0 = kbeg; k0 < kbeg + kslice; k0 += 16) {
        // ---- A tile: u[row][d0..d0+3] computed from conv(x)
        {
            int row = bm + ar;                   // token, < 2048
            int d0  = k0 + ac4;
            int lpos = row & (SEQ - 1);
            const float* xr = xz + (size_t)row * 4096 + d0;
            float4 x0  = *(const float4*)xr;
            float4 xm1 = make_float4(0.f, 0.f, 0.f, 0.f), xm2 = xm1, xm3 = xm1;
            if (lpos >= 1) xm1 = *(const float4*)(xr - 4096);
            if (lpos >= 2) xm2 = *(const float4*)(xr - 8192);
            if (lpos >= 3) xm3 = *(const float4*)(xr - 12288);
            float4 cb = *(const float4*)(convb + d0);
            float4 c0 = *(const float4*)(convw + (size_t)(d0 + 0) * 4);
            float4 c1 = *(const float4*)(convw + (size_t)(d0 + 1) * 4);
            float4 c2 = *(const float4*)(convw + (size_t)(d0 + 2) * 4);
            float4 c3 = *(const float4*)(convw + (size_t)(d0 + 3) * 4);
            float4 av;
            av.x = siluf(cb.x + c0.x * xm3.x + c0.y * xm2.x + c0.z * xm1.x + c0.w * x0.x);
            av.y = siluf(cb.y + c1.x * xm3.y + c1.y * xm2.y + c1.z * xm1.y + c1.w * x0.y);
            av.z = siluf(cb.z + c2.x * xm3.z + c2.y * xm2.z + c2.z * xm1.z + c2.w * x0.z);
            av.w = siluf(cb.w + c3.x * xm3.w + c3.y * xm2.w + c3.z * xm1.w + c3.w * x0.w);
            As[ac4 + 0][ar] = av.x; As[ac4 + 1][ar] = av.y;
            As[ac4 + 2][ar] = av.z; As[ac4 + 3][ar] = av.w;
        }
        // ---- B tile (N=96, guarded)
        {
            int col = bn + bc4;
            float4 bv = make_float4(0.f, 0.f, 0.f, 0.f);
            const float* bp = B + (size_t)(k0 + bkr) * 96 + col;
            if (col + 3 < 96) {
                bv = *(const float4*)bp;
            } else {
                if (col + 0 < 96) bv.x = bp[0];
                if (col + 1 < 96) bv.y = bp[1];
                if (col + 2 < 96) bv.z = bp[2];
                if (col + 3 < 96) bv.w = bp[3];
            }
            Bs[bkr][bc4 + 0] = bv.x; Bs[bkr][bc4 + 1] = bv.y;
            Bs[bkr][bc4 + 2] = bv.z; Bs[bkr][bc4 + 3] = bv.w;
        }

        __syncthreads();

        #pragma unroll
        for (int kk = 0; kk < 16; ++kk) {
            float a[4], b[4];
            #pragma unroll
            for (int i = 0; i < 4; ++i) a[i] = As[kk][ty * 4 + i];
            #pragma unroll
            for (int j = 0; j < 4; ++j) b[j] = Bs[kk][tx * 4 + j];
            #pragma unroll
            for (int i = 0; i < 4; ++i)
                #pragma unroll
                for (int j = 0; j < 4; ++j)
                    acc[i][j] = fmaf(a[i], b[j], acc[i][j]);
        }
        __syncthreads();
    }

    float* dst = part + (size_t)blockIdx.z * NTOK * 96;
    #pragma unroll
    for (int i = 0; i < 4; ++i) {
        int row = bm + ty * 4 + i;
        #pragma unroll
        for (int j = 0; j < 4; ++j) {
            int col = bn + tx * 4 + j;
            if (col >= 96) continue;
            dst[(size_t)row * 96 + col] = acc[i][j];
        }
    }
}

__global__ __launch_bounds__(256)
void reduce_splitk(const float* __restrict__ part, float* __restrict__ out,
                   int n, int S)
{
    int i = blockIdx.x * 256 + threadIdx.x;
    if (i >= n) return;
    float s = 0.f;
    for (int j = 0; j < S; ++j) s += part[(size_t)j * n + i];
    out[i] = s;
}

// ---------------------------------------------------------------------------
// Chunk-parallel selective scan — 2 threads per (b,chunk,d), 8 states each;
// depthwise conv+SiLU fused via 4-tap rolling register window over x.
// Explicit 1-deep register pipeline. State layout [b][c][d][16].
// ---------------------------------------------------------------------------
__global__ __launch_bounds__(256)
void scan_pass1(const float* __restrict__ delta, const float* __restrict__ xz,
                const float* __restrict__ convw, const float* __restrict__ convb,
                const float* __restrict__ xdbl, const float* __restrict__ A_log,
                float* __restrict__ Aprod, float* __restrict__ Hend)
{
    int gid = blockIdx.x * 256 + threadIdx.x;   // over B*CHUNKS*D*2
    if (gid >= BATCH * CHUNKS * D_INNER * 2) return;
    int lane = gid & 63;
    int wv   = gid >> 6;
    int dsub = lane & 31, nh = lane >> 5;
    int dblk = wv & 63;
    int c    = (wv >> 6) & (CHUNKS - 1);
    int b    = wv >> (6 + LOG2C);
    int d    = dblk * 32 + dsub;

    float An[8];
    {
        const float4* a4 = (const float4*)(A_log + d * 16 + nh * 8);
        #pragma unroll
        for (int q = 0; q < 2; ++q) {
            float4 v = a4[q];
            An[q * 4 + 0] = -__expf(v.x);
            An[q * 4 + 1] = -__expf(v.y);
            An[q * 4 + 2] = -__expf(v.z);
            An[q * 4 + 3] = -__expf(v.w);
        }
    }
    float4 cw = *(const float4*)(convw + (size_t)d * 4);
    float  cb = convb[d];

    const float* dp = delta + ((size_t)b * SEQ + c * LC) * D_INNER + d;
    const float* xp = xz    + ((size_t)b * SEQ + c * LC) * 4096 + d;
    const float* xb = xdbl  + ((size_t)b * SEQ + c * LC) * 96 + DT_RANK + nh * 8;

    float h[8], ap[8];
    #pragma unroll
    for (int n = 0; n < 8; ++n) { h[n] = 0.f; ap[n] = 1.f; }

    // conv window prologue (c uniform across wave -> no divergence)
    float xw1 = 0.f, xw2 = 0.f, xw3 = 0.f;
    if (c > 0) {
        xw1 = xp[-4096];
        xw2 = xp[-2 * 4096];
        xw3 = xp[-3 * 4096];
    }

    float  dt = dp[0];
    float  x0 = xp[0];
    float4 Bq0 = *(const float4*)(xb);
    float4 Bq1 = *(const float4*)(xb + 4);

    for (int l = 0; l < LC - 1; ++l) {
        float  dt_n = dp[(size_t)(l + 1) * D_INNER];
        float  x0n  = xp[(size_t)(l + 1) * 4096];
        float4 B0n  = *(const float4*)(xb + (l + 1) * 96);
        float4 B1n  = *(const float4*)(xb + (l + 1) * 96 + 4);

        float ut = siluf(cb + cw.x * xw3 + cw.y * xw2 + cw.z * xw1 + cw.w * x0);
        float Bv[8] = { Bq0.x, Bq0.y, Bq0.z, Bq0.w, Bq1.x, Bq1.y, Bq1.z, Bq1.w };
        float dtu = dt * ut;
        #pragma unroll
        for (int n = 0; n < 8; ++n) {
            float da = __expf(dt * An[n]);
            h[n]  = fmaf(da, h[n], dtu * Bv[n]);
            ap[n] *= da;
        }
        xw3 = xw2; xw2 = xw1; xw1 = x0; x0 = x0n;
        dt = dt_n; Bq0 = B0n; Bq1 = B1n;
    }
    {   // final step
        float ut = siluf(cb + cw.x * xw3 + cw.y * xw2 + cw.z * xw1 + cw.w * x0);
        float Bv[8] = { Bq0.x, Bq0.y, Bq0.z, Bq0.w, Bq1.x, Bq1.y, Bq1.z, Bq1.w };
        float dtu = dt * ut;
        #pragma unroll
        for (int n = 0; n < 8; ++n) {
            float da = __expf(dt * An[n]);
            h[n]  = fmaf(da, h[n], dtu * Bv[n]);
            ap[n] *= da;
        }
    }

    size_t off = ((((size_t)b * CHUNKS + c) * D_INNER) + d) * 16 + nh * 8;
    *(float4*)(Hend  + off)     = make_float4(h[0], h[1], h[2], h[3]);
    *(float4*)(Hend  + off + 4) = make_float4(h[4], h[5], h[6], h[7]);
    *(float4*)(Aprod + off)     = make_float4(ap[0], ap[1], ap[2], ap[3]);
    *(float4*)(Aprod + off + 4) = make_float4(ap[4], ap[5], ap[6], ap[7]);
}

__global__ __launch_bounds__(256)
void scan_pass2(const float* __restrict__ Aprod, float* __restrict__ HendHin)
{
    int idx = blockIdx.x * 256 + threadIdx.x;      // (b*D + d)*16 + n
    if (idx >= BATCH * D_INNER * D_STATE) return;
    int n = idx & 15;
    int d = (idx >> 4) & (D_INNER - 1);
    int b = idx >> 15;

    float h = 0.f;
    for (int c = 0; c < CHUNKS; ++c) {
        size_t j = ((((size_t)b * CHUNKS + c) * D_INNER) + d) * 16 + n;
        float ap = Aprod[j];
        float he = HendHin[j];
        HendHin[j] = h;            // Hend -> Hin in place (read-before-write)
        h = ap * h + he;
    }
}

// pass 3: replay from Hin + C-proj + D-skip + silu(res) gate; conv fused;
// writes fp16 yg into its own region (ld 2048).
__global__ __launch_bounds__(256)
void scan_pass3(const float* __restrict__ delta, const float* __restrict__ xz,
                const float* __restrict__ convw, const float* __restrict__ convb,
                const float* __restrict__ xdbl, const float* __restrict__ A_log,
                const float* __restrict__ D_skip, const float* __restrict__ Hin,
                _Float16* __restrict__ ygh)
{
    int gid = blockIdx.x * 256 + threadIdx.x;   // over B*CHUNKS*D*2
    if (gid >= BATCH * CHUNKS * D_INNER * 2) return;
    int lane = gid & 63;
    int wv   = gid >> 6;
    int dsub = lane & 31, nh = lane >> 5;
    int dblk = wv & 63;
    int c    = (wv >> 6) & (CHUNKS - 1);
    int b    = wv >> (6 + LOG2C);
    int d    = dblk * 32 + dsub;

    float An[8];
    {
        const float4* a4 = (const float4*)(A_log + d * 16 + nh * 8);
        #pragma unroll
        for (int q = 0; q < 2; ++q) {
            float4 v = a4[q];
            An[q * 4 + 0] = -__expf(v.x);
            An[q * 4 + 1] = -__expf(v.y);
            An[q * 4 + 2] = -__expf(v.z);
            An[q * 4 + 3] = -__expf(v.w);
        }
    }
    float4 cw = *(const float4*)(convw + (size_t)d * 4);
    float  cb = convb[d];
    float  Dd = D_skip[d];

    float h[8];
    {
        size_t off = ((((size_t)b * CHUNKS + c) * D_INNER) + d) * 16 + nh * 8;
        float4 v0 = *(const float4*)(Hin + off);
        float4 v1 = *(const float4*)(Hin + off + 4);
        h[0] = v0.x; h[1] = v0.y; h[2] = v0.z; h[3] = v0.w;
        h[4] = v1.x; h[5] = v1.y; h[6] = v1.z; h[7] = v1.w;
    }

    const float* dp = delta + ((size_t)b * SEQ + c * LC) * D_INNER + d;
    const float* xp = xz    + ((size_t)b * SEQ + c * LC) * 4096 + d;
    const float* rp = xp + D_INNER;                 // res half of the same rows
    const float* xb = xdbl  + ((size_t)b * SEQ + c * LC) * 96 + DT_RANK + nh * 8;
    _Float16*    yp = ygh   + ((size_t)b * SEQ + c * LC) * 2048 + d;

    // conv window prologue
    float xw1 = 0.f, xw2 = 0.f, xw3 = 0.f;
    if (c > 0) {
        xw1 = xp[-4096];
        xw2 = xp[-2 * 4096];
        xw3 = xp[-3 * 4096];
    }

    float  dt = dp[0], x0 = xp[0], res = rp[0];
    float4 Bq0 = *(const float4*)(xb);
    float4 Bq1 = *(const float4*)(xb + 4);
    float4 Cq0 = *(const float4*)(xb + 16);
    float4 Cq1 = *(const float4*)(xb + 20);

    for (int l = 0; l < LC; ++l) {
        float dt_n, x0n, res_n;
        float4 B0n, B1n, C0n, C1n;
        if (l + 1 < LC) {
            dt_n  = dp[(size_t)(l + 1) * D_INNER];
            x0n   = xp[(size_t)(l + 1) * 4096];
            res_n = rp[(size_t)(l + 1) * 4096];
            B0n = *(const float4*)(xb + (l + 1) * 96);
            B1n = *(const float4*)(xb + (l + 1) * 96 + 4);
            C0n = *(const float4*)(xb + (l + 1) * 96 + 16);
            C1n = *(const float4*)(xb + (l + 1) * 96 + 20);
        }

        float ut = siluf(cb + cw.x * xw3 + cw.y * xw2 + cw.z * xw1 + cw.w * x0);
        float Bv[8] = { Bq0.x, Bq0.y, Bq0.z, Bq0.w, Bq1.x, Bq1.y, Bq1.z, Bq1.w };
        float Cv[8] = { Cq0.x, Cq0.y, Cq0.z, Cq0.w, Cq1.x, Cq1.y, Cq1.z, Cq1.w };
        float dtu = dt * ut;
        float y = 0.f;
        #pragma unroll
        for (int n = 0; n < 8; ++n) {
            float da = __expf(dt * An[n]);
            h[n] = fmaf(da, h[n], dtu * Bv[n]);
            y = fmaf(h[n], Cv[n], y);
        }
        y += __shfl_xor(y, 32, 64);              // combine the two n-halves
        if (nh == 0)
            yp[(size_t)l * 2048] = (_Float16)((y + ut * Dd) * siluf(res));

        xw3 = xw2; xw2 = xw1; xw1 = x0; x0 = x0n;
        dt = dt_n; res = res_n;
        Bq0 = B0n; Bq1 = B1n; Cq0 = C0n; Cq1 = C1n;
    }
}

// ---------------------------------------------------------------------------
extern "C" void kernel_launch(void* const* d_in, const int* in_sizes, int n_in,
                              void* d_out, int out_size, void* d_ws, size_t ws_size,
                              hipStream_t stream)
{
    const float* H      = (const float*)d_in[0];
    const float* Win    = (const float*)d_in[1];
    const float* convw  = (const float*)d_in[2];
    const float* convb  = (const float*)d_in[3];
    const float* xprojw = (const float*)d_in[4];
    const float* dtw    = (const float*)d_in[5];
    const float* dtb    = (const float*)d_in[6];
    const float* Alog   = (const float*)d_in[7];
    const float* Dskip  = (const float*)d_in[8];
    const float* Wout   = (const float*)d_in[9];
    float* out = (float*)d_out;

    float* ws    = (float*)d_ws;
    float* xz    = ws;                                   // [NTOK,4096] 32MB
    float* slotB = xz   + (size_t)NTOK * 4096;           // 16MB (Woutp + ygh)
    float* xdbl  = slotB + (size_t)NTOK * 2048;          // 0.75MB
    float* delta = xdbl + (size_t)NTOK * 96;             // 16MB
    float* Aprod = delta + (size_t)NTOK * 2048;          // 8MB
    float* Hend  = Aprod + (size_t)BATCH * CHUNKS * D_INNER * 16;  // 8MB

    // aliases (lifetime-disjoint):
    _Float16* Hh    = (_Float16*)delta;                  // 4MB, dead after GEMM1
    _Float16* Winp  = (_Float16*)delta + 2 * 1024 * 1024;// 8MB, dead after GEMM1
    float*    part  = delta;                             // GEMM2 partials (12.6MB)
    float*    part4 = delta;                             // GEMM4 partials (16MB)
    _Float16* Woutp = (_Float16*)slotB;                  // 4MB
    _Float16* ygh   = (_Float16*)slotB + 2 * 1024 * 1024;// 8MB, ld 2048

    dim3 blk(256);

    // 0) prep: Hh = fp16(H); Winp = pack(Win); Woutp = pack(Wout)
    prep_kernel<<<5120, blk, 0, stream>>>(H, Win, Wout, Hh, Winp, Woutp);

    // 1) xz = H @ Win   (MFMA fp16; 1024 wg)
    gemm_f16_mfma<<<dim3((4096 / 64) * (NTOK / 128), 1, 1), blk, 0, stream>>>(
        Hh, Winp, xz, NTOK, 2 * D_INNER, D_MODEL, D_MODEL, 2 * D_INNER);

    // 2) x_dbl = silu(conv(x)+cb) @ x_proj_w  — fused conv, split-K z=16
    gemm2_conv_splitk<<<dim3(2, NTOK / 64, 16), blk, 0, stream>>>(
        xz, convw, convb, xprojw, part);
    reduce_splitk<<<(NTOK * 96 + 255) / 256, blk, 0, stream>>>(
        part, xdbl, NTOK * 96, 16);

    // 3) delta = softplus(x_dbl[:, :64] @ dt_proj_w + dt_proj_b)
    gemm_f32<true, true><<<dim3(D_INNER / 64, NTOK / 64), blk, 0, stream>>>(
        xdbl, dtw, dtb, delta, NTOK, D_INNER, DT_RANK, 96, D_INNER, D_INNER);

    // 4) chunk-parallel scan (half-wave n-split, register pipeline, fused conv)
    {
        int nthr2 = BATCH * CHUNKS * D_INNER * 2;        // 262,144
        scan_pass1<<<nthr2 / 256, blk, 0, stream>>>(delta, xz, convw, convb,
                                                    xdbl, Alog, Aprod, Hend);
        scan_pass2<<<(BATCH * D_INNER * 16) / 256, blk, 0, stream>>>(Aprod, Hend);
        scan_pass3<<<nthr2 / 256, blk, 0, stream>>>(delta, xz, convw, convb,
                                                    xdbl, Alog, Dskip,
                                                    Hend /*Hin*/, ygh);
    }

    // 5) out = yg @ Wout   (MFMA fp16; split-K=2)
    gemm_f16_mfma<<<dim3((1024 / 64) * (NTOK / 128), 1, 2), blk, 0, stream>>>(
        ygh, Woutp, part4, NTOK, D_MODEL, D_INNER, D_INNER, D_MODEL);
    reduce_splitk<<<(NTOK * D_MODEL) / 256, blk, 0, stream>>>(
        part4, out, NTOK * D_MODEL, 2);
}

// Round 12
// 288.332 us; speedup vs baseline: 1.1804x; 1.0073x over previous
//
#include <hip/hip_runtime.h>
#include <hip/hip_bf16.h>
#include <cstdint>

#define D_MODEL  1024
#define D_INNER  2048
#define D_STATE  16
#define DT_RANK  64
#define KERW     4
#define BATCH    2
#define SEQ      1024
#define NTOK     (BATCH * SEQ)
#define CHUNKS   32
#define LOG2C    5
#define LC       (SEQ / CHUNKS)     // 32 steps per chunk

typedef _Float16 h8 __attribute__((ext_vector_type(8)));
typedef _Float16 h4 __attribute__((ext_vector_type(4)));
typedef float    f32x4 __attribute__((ext_vector_type(4)));

__device__ __forceinline__ float siluf(float x) {
    return x / (1.f + __expf(-x));
}

#define GLOAD_LDS16(g, p) __builtin_amdgcn_global_load_lds( \
    (const __attribute__((address_space(1))) void*)(g),      \
    (__attribute__((address_space(3))) void*)(p), 16, 0, 0)

// ---------------------------------------------------------------------------
// Prep (one dispatch): H->fp16 ; pack Win ; pack Wout.
// ---------------------------------------------------------------------------
__global__ __launch_bounds__(256)
void prep_kernel(const float* __restrict__ H, const float* __restrict__ Win,
                 const float* __restrict__ Wout, _Float16* __restrict__ Hh,
                 _Float16* __restrict__ Winp, _Float16* __restrict__ Woutp)
{
    int bid = blockIdx.x;
    int tid = threadIdx.x;
    if (bid < 2048) {                       // H -> fp16 (x4)
        int i = bid * 256 + tid;
        float4 v = ((const float4*)H)[i];
        h4 h = { (_Float16)v.x, (_Float16)v.y, (_Float16)v.z, (_Float16)v.w };
        *(h4*)(Hh + (size_t)i * 4) = h;
    } else if (bid < 4096) {                // pack Win (NN=4096)
        int gid = (bid - 2048) * 256 + tid;
        int n  = gid & 4095;
        int kb = gid >> 12;
        h8 v;
        #pragma unroll
        for (int j = 0; j < 8; ++j)
            v[j] = (_Float16)Win[(size_t)(kb * 8 + j) * 4096 + n];
        *(h8*)(Winp + (size_t)gid * 8) = v;
    } else {                                // pack Wout (NN=1024)
        int gid = (bid - 4096) * 256 + tid;
        int n  = gid & 1023;
        int kb = gid >> 10;
        h8 v;
        #pragma unroll
        for (int j = 0; j < 8; ++j)
            v[j] = (_Float16)Wout[(size_t)(kb * 8 + j) * 1024 + n];
        *(h8*)(Woutp + (size_t)gid * 8) = v;
    }
}

// ---------------------------------------------------------------------------
// fp16 MFMA GEMM: BM=128, BN=64, BK=64, 4 waves (2x2), 2-stage LDS dbuf.
// bn-sliced XCD mapping: each XCD owns nbn/8 bn-columns x all bm rows so its
// B working set (<=1MB) stays L2-resident (requires nbn % 8 == 0).
// Optional split-K via gridDim.z (partial z writes C + z*M*ldc).
// LDS: 2 x (16KB A + 8KB B) = 48 KB -> 3 blocks/CU.
// ---------------------------------------------------------------------------
__device__ __forceinline__ void stage_tiles(
    const _Float16* __restrict__ A, const _Float16* __restrict__ Bp,
    _Float16* as, _Float16* bs, int bm, int bn, int k0, int N, int lda, int tid)
{
    // A tile: 8 kgc x 128 rows = 1024 chunks of 16B
    #pragma unroll
    for (int i = 0; i < 4; ++i) {
        int c = i * 256 + tid;
        int row = c & 127, kgc = c >> 7;
        const _Float16* g = A + (size_t)(bm + row) * lda + k0 + kgc * 8;
        GLOAD_LDS16(g, as + (size_t)c * 8);
    }
    // B tile: 8 kgc x 64 cols = 512 chunks
    #pragma unroll
    for (int i = 0; i < 2; ++i) {
        int c = i * 256 + tid;
        int col = c & 63, kgc = c >> 6;
        const _Float16* g = Bp + ((size_t)((k0 >> 3) + kgc) * N + bn + col) * 8;
        GLOAD_LDS16(g, bs + (size_t)c * 8);
    }
}

__global__ __launch_bounds__(256)
void gemm_f16_mfma(const _Float16* __restrict__ A, const _Float16* __restrict__ Bp,
                   float* __restrict__ C, int M, int N, int K, int lda, int ldc)
{
    __shared__ alignas(16) _Float16 As[2][8 * 128 * 8];   // 2 x 16 KB
    __shared__ alignas(16) _Float16 Bs[2][8 * 64 * 8];    // 2 x 8 KB

    const int tid = threadIdx.x;
    const int l = tid & 63, w = tid >> 6;
    const int wm = w >> 1, wn = w & 1;          // 2x2 waves, 64x32 each

    // bn-sliced XCD mapping
    const int nbn = N >> 6;
    const int cpx = nbn >> 3;                   // bn-blocks per XCD
    const int xcd = blockIdx.x & 7;
    const int wgl = blockIdx.x >> 3;
    const int bm  = (wgl / cpx) * 128;
    const int bn  = (xcd * cpx + (wgl % cpx)) * 64;

    const int kslice = K / gridDim.z;
    const int kbeg = blockIdx.z * kslice;
    const int kend = kbeg + kslice;

    f32x4 acc[4][2] = {};
    const int kg = l >> 4, r = l & 15;

    stage_tiles(A, Bp, As[0], Bs[0], bm, bn, kbeg, N, lda, tid);
    __syncthreads();                            // drains vmcnt(0)

    int cur = 0;
    for (int k0 = kbeg; k0 < kend; k0 += 64) {
        if (k0 + 64 < kend)
            stage_tiles(A, Bp, As[cur ^ 1], Bs[cur ^ 1], bm, bn, k0 + 64, N, lda, tid);

        #pragma unroll
        for (int kk = 0; kk < 2; ++kk) {
            h8 a[4], b[2];
            #pragma unroll
            for (int mi = 0; mi < 4; ++mi)
                a[mi] = *(const h8*)(As[cur]
                        + (size_t)((kk * 4 + kg) * 128 + wm * 64 + mi * 16 + r) * 8);
            #pragma unroll
            for (int ni = 0; ni < 2; ++ni)
                b[ni] = *(const h8*)(Bs[cur]
                        + (size_t)((kk * 4 + kg) * 64 + wn * 32 + ni * 16 + r) * 8);

            #pragma unroll
            for (int mi = 0; mi < 4; ++mi)
                #pragma unroll
                for (int ni = 0; ni < 2; ++ni)
                    acc[mi][ni] = __builtin_amdgcn_mfma_f32_16x16x32_f16(
                        a[mi], b[ni], acc[mi][ni], 0, 0, 0);
        }

        __syncthreads();
        cur ^= 1;
    }

    // C/D layout: col = lane&15, row = (lane>>4)*4 + reg  [m89-verified]
    float* dst = C + (size_t)blockIdx.z * M * ldc;
    const int q = l >> 4;
    #pragma unroll
    for (int mi = 0; mi < 4; ++mi)
        #pragma unroll
        for (int ni = 0; ni < 2; ++ni)
            #pragma unroll
            for (int j = 0; j < 4; ++j)
                dst[(size_t)(bm + wm * 64 + mi * 16 + q * 4 + j) * ldc
                    + (bn + wn * 32 + ni * 16 + r)] = acc[mi][ni][j];
}

// ---------------------------------------------------------------------------
// Generic fp32 GEMM (GEMM3 only): 64x64 tile.
// ---------------------------------------------------------------------------
template<bool BIAS, bool SOFTPLUS>
__global__ __launch_bounds__(256)
void gemm_f32(const float* __restrict__ A, const float* __restrict__ B,
              const float* __restrict__ bias, float* __restrict__ C,
              int M, int N, int K, int lda, int ldb, int ldc)
{
    __shared__ float As[16][68];
    __shared__ float Bs[16][68];
    const int tid = threadIdx.x;
    const int tx = tid & 15, ty = tid >> 4;
    const int bm = blockIdx.y * 64, bn = blockIdx.x * 64;

    float acc[4][4] = {};

    const int ar  = tid >> 2;
    const int ac4 = (tid & 3) << 2;
    const int bkr = tid >> 4;
    const int bc4 = (tid & 15) << 2;

    for (int k0 = 0; k0 < K; k0 += 16) {
        float4 av = make_float4(0.f, 0.f, 0.f, 0.f);
        {
            int row = bm + ar;
            if (row < M)
                av = *(const float4*)(A + (size_t)row * lda + (k0 + ac4));
        }
        As[ac4 + 0][ar] = av.x; As[ac4 + 1][ar] = av.y;
        As[ac4 + 2][ar] = av.z; As[ac4 + 3][ar] = av.w;

        float4 bv = make_float4(0.f, 0.f, 0.f, 0.f);
        {
            int col = bn + bc4;
            const float* bp = B + (size_t)(k0 + bkr) * ldb + col;
            if (col + 3 < N) {
                bv = *(const float4*)bp;
            } else {
                if (col + 0 < N) bv.x = bp[0];
                if (col + 1 < N) bv.y = bp[1];
                if (col + 2 < N) bv.z = bp[2];
                if (col + 3 < N) bv.w = bp[3];
            }
        }
        Bs[bkr][bc4 + 0] = bv.x; Bs[bkr][bc4 + 1] = bv.y;
        Bs[bkr][bc4 + 2] = bv.z; Bs[bkr][bc4 + 3] = bv.w;

        __syncthreads();

        #pragma unroll
        for (int kk = 0; kk < 16; ++kk) {
            float a[4], b[4];
            #pragma unroll
            for (int i = 0; i < 4; ++i) a[i] = As[kk][ty * 4 + i];
            #pragma unroll
            for (int j = 0; j < 4; ++j) b[j] = Bs[kk][tx * 4 + j];
            #pragma unroll
            for (int i = 0; i < 4; ++i)
                #pragma unroll
                for (int j = 0; j < 4; ++j)
                    acc[i][j] = fmaf(a[i], b[j], acc[i][j]);
        }
        __syncthreads();
    }

    #pragma unroll
    for (int i = 0; i < 4; ++i) {
        int row = bm + ty * 4 + i;
        if (row >= M) continue;
        #pragma unroll
        for (int j = 0; j < 4; ++j) {
            int col = bn + tx * 4 + j;
            if (col >= N) continue;
            float v = acc[i][j];
            if (BIAS) v += bias[col];
            if (SOFTPLUS) v = (v > 20.f) ? v : log1pf(__expf(v));
            C[(size_t)row * ldc + col] = v;
        }
    }
}

// ---------------------------------------------------------------------------
// GEMM2 with FUSED depthwise conv + SiLU on the A operand (split-K).
// ---------------------------------------------------------------------------
__global__ __launch_bounds__(256)
void gemm2_conv_splitk(const float* __restrict__ xz, const float* __restrict__ convw,
                       const float* __restrict__ convb, const float* __restrict__ B,
                       float* __restrict__ part)
{
    __shared__ float As[16][68];
    __shared__ float Bs[16][68];
    const int tid = threadIdx.x;
    const int tx = tid & 15, ty = tid >> 4;
    const int bm = blockIdx.y * 64, bn = blockIdx.x * 64;
    const int kslice = D_INNER / gridDim.z;
    const int kbeg = blockIdx.z * kslice;

    float acc[4][4] = {};

    const int ar  = tid >> 2;
    const int ac4 = (tid & 3) << 2;
    const int bkr = tid >> 4;
    const int bc4 = (tid & 15) << 2;

    for (int k0 = kbeg; k0 < kbeg + kslice; k0 += 16) {
        {
            int row = bm + ar;
            int d0  = k0 + ac4;
            int lpos = row & (SEQ - 1);
            const float* xr = xz + (size_t)row * 4096 + d0;
            float4 x0  = *(const float4*)xr;
            float4 xm1 = make_float4(0.f, 0.f, 0.f, 0.f), xm2 = xm1, xm3 = xm1;
            if (lpos >= 1) xm1 = *(const float4*)(xr - 4096);
            if (lpos >= 2) xm2 = *(const float4*)(xr - 8192);
            if (lpos >= 3) xm3 = *(const float4*)(xr - 12288);
            float4 cb = *(const float4*)(convb + d0);
            float4 c0 = *(const float4*)(convw + (size_t)(d0 + 0) * 4);
            float4 c1 = *(const float4*)(convw + (size_t)(d0 + 1) * 4);
            float4 c2 = *(const float4*)(convw + (size_t)(d0 + 2) * 4);
            float4 c3 = *(const float4*)(convw + (size_t)(d0 + 3) * 4);
            float4 av;
            av.x = siluf(cb.x + c0.x * xm3.x + c0.y * xm2.x + c0.z * xm1.x + c0.w * x0.x);
            av.y = siluf(cb.y + c1.x * xm3.y + c1.y * xm2.y + c1.z * xm1.y + c1.w * x0.y);
            av.z = siluf(cb.z + c2.x * xm3.z + c2.y * xm2.z + c2.z * xm1.z + c2.w * x0.z);
            av.w = siluf(cb.w + c3.x * xm3.w + c3.y * xm2.w + c3.z * xm1.w + c3.w * x0.w);
            As[ac4 + 0][ar] = av.x; As[ac4 + 1][ar] = av.y;
            As[ac4 + 2][ar] = av.z; As[ac4 + 3][ar] = av.w;
        }
        {
            int col = bn + bc4;
            float4 bv = make_float4(0.f, 0.f, 0.f, 0.f);
            const float* bp = B + (size_t)(k0 + bkr) * 96 + col;
            if (col + 3 < 96) {
                bv = *(const float4*)bp;
            } else {
                if (col + 0 < 96) bv.x = bp[0];
                if (col + 1 < 96) bv.y = bp[1];
                if (col + 2 < 96) bv.z = bp[2];
                if (col + 3 < 96) bv.w = bp[3];
            }
            Bs[bkr][bc4 + 0] = bv.x; Bs[bkr][bc4 + 1] = bv.y;
            Bs[bkr][bc4 + 2] = bv.z; Bs[bkr][bc4 + 3] = bv.w;
        }

        __syncthreads();

        #pragma unroll
        for (int kk = 0; kk < 16; ++kk) {
            float a[4], b[4];
            #pragma unroll
            for (int i = 0; i < 4; ++i) a[i] = As[kk][ty * 4 + i];
            #pragma unroll
            for (int j = 0; j < 4; ++j) b[j] = Bs[kk][tx * 4 + j];
            #pragma unroll
            for (int i = 0; i < 4; ++i)
                #pragma unroll
                for (int j = 0; j < 4; ++j)
                    acc[i][j] = fmaf(a[i], b[j], acc[i][j]);
        }
        __syncthreads();
    }

    float* dst = part + (size_t)blockIdx.z * NTOK * 96;
    #pragma unroll
    for (int i = 0; i < 4; ++i) {
        int row = bm + ty * 4 + i;
        #pragma unroll
        for (int j = 0; j < 4; ++j) {
            int col = bn + tx * 4 + j;
            if (col >= 96) continue;
            dst[(size_t)row * 96 + col] = acc[i][j];
        }
    }
}

__global__ __launch_bounds__(256)
void reduce_splitk(const float* __restrict__ part, float* __restrict__ out,
                   int n, int S)
{
    int i = blockIdx.x * 256 + threadIdx.x;
    if (i >= n) return;
    float s = 0.f;
    for (int j = 0; j < S; ++j) s += part[(size_t)j * n + i];
    out[i] = s;
}

// ---------------------------------------------------------------------------
// Chunk-parallel selective scan — 2 threads per (b,chunk,d), 8 states each;
// conv+SiLU fused via 4-tap rolling window; 1-deep register pipeline.
// ---------------------------------------------------------------------------
__global__ __launch_bounds__(256)
void scan_pass1(const float* __restrict__ delta, const float* __restrict__ xz,
                const float* __restrict__ convw, const float* __restrict__ convb,
                const float* __restrict__ xdbl, const float* __restrict__ A_log,
                float* __restrict__ Aprod, float* __restrict__ Hend)
{
    int gid = blockIdx.x * 256 + threadIdx.x;   // over B*CHUNKS*D*2
    if (gid >= BATCH * CHUNKS * D_INNER * 2) return;
    int lane = gid & 63;
    int wv   = gid >> 6;
    int dsub = lane & 31, nh = lane >> 5;
    int dblk = wv & 63;
    int c    = (wv >> 6) & (CHUNKS - 1);
    int b    = wv >> (6 + LOG2C);
    int d    = dblk * 32 + dsub;

    float An[8];
    {
        const float4* a4 = (const float4*)(A_log + d * 16 + nh * 8);
        #pragma unroll
        for (int q = 0; q < 2; ++q) {
            float4 v = a4[q];
            An[q * 4 + 0] = -__expf(v.x);
            An[q * 4 + 1] = -__expf(v.y);
            An[q * 4 + 2] = -__expf(v.z);
            An[q * 4 + 3] = -__expf(v.w);
        }
    }
    float4 cw = *(const float4*)(convw + (size_t)d * 4);
    float  cb = convb[d];

    const float* dp = delta + ((size_t)b * SEQ + c * LC) * D_INNER + d;
    const float* xp = xz    + ((size_t)b * SEQ + c * LC) * 4096 + d;
    const float* xb = xdbl  + ((size_t)b * SEQ + c * LC) * 96 + DT_RANK + nh * 8;

    float h[8], ap[8];
    #pragma unroll
    for (int n = 0; n < 8; ++n) { h[n] = 0.f; ap[n] = 1.f; }

    float xw1 = 0.f, xw2 = 0.f, xw3 = 0.f;
    if (c > 0) {
        xw1 = xp[-4096];
        xw2 = xp[-2 * 4096];
        xw3 = xp[-3 * 4096];
    }

    float  dt = dp[0];
    float  x0 = xp[0];
    float4 Bq0 = *(const float4*)(xb);
    float4 Bq1 = *(const float4*)(xb + 4);

    for (int l = 0; l < LC - 1; ++l) {
        float  dt_n = dp[(size_t)(l + 1) * D_INNER];
        float  x0n  = xp[(size_t)(l + 1) * 4096];
        float4 B0n  = *(const float4*)(xb + (l + 1) * 96);
        float4 B1n  = *(const float4*)(xb + (l + 1) * 96 + 4);

        float ut = siluf(cb + cw.x * xw3 + cw.y * xw2 + cw.z * xw1 + cw.w * x0);
        float Bv[8] = { Bq0.x, Bq0.y, Bq0.z, Bq0.w, Bq1.x, Bq1.y, Bq1.z, Bq1.w };
        float dtu = dt * ut;
        #pragma unroll
        for (int n = 0; n < 8; ++n) {
            float da = __expf(dt * An[n]);
            h[n]  = fmaf(da, h[n], dtu * Bv[n]);
            ap[n] *= da;
        }
        xw3 = xw2; xw2 = xw1; xw1 = x0; x0 = x0n;
        dt = dt_n; Bq0 = B0n; Bq1 = B1n;
    }
    {
        float ut = siluf(cb + cw.x * xw3 + cw.y * xw2 + cw.z * xw1 + cw.w * x0);
        float Bv[8] = { Bq0.x, Bq0.y, Bq0.z, Bq0.w, Bq1.x, Bq1.y, Bq1.z, Bq1.w };
        float dtu = dt * ut;
        #pragma unroll
        for (int n = 0; n < 8; ++n) {
            float da = __expf(dt * An[n]);
            h[n]  = fmaf(da, h[n], dtu * Bv[n]);
            ap[n] *= da;
        }
    }

    size_t off = ((((size_t)b * CHUNKS + c) * D_INNER) + d) * 16 + nh * 8;
    *(float4*)(Hend  + off)     = make_float4(h[0], h[1], h[2], h[3]);
    *(float4*)(Hend  + off + 4) = make_float4(h[4], h[5], h[6], h[7]);
    *(float4*)(Aprod + off)     = make_float4(ap[0], ap[1], ap[2], ap[3]);
    *(float4*)(Aprod + off + 4) = make_float4(ap[4], ap[5], ap[6], ap[7]);
}

__global__ __launch_bounds__(256)
void scan_pass2(const float* __restrict__ Aprod, float* __restrict__ HendHin)
{
    int idx = blockIdx.x * 256 + threadIdx.x;      // (b*D + d)*16 + n
    if (idx >= BATCH * D_INNER * D_STATE) return;
    int n = idx & 15;
    int d = (idx >> 4) & (D_INNER - 1);
    int b = idx >> 15;

    float h = 0.f;
    for (int c = 0; c < CHUNKS; ++c) {
        size_t j = ((((size_t)b * CHUNKS + c) * D_INNER) + d) * 16 + n;
        float ap = Aprod[j];
        float he = HendHin[j];
        HendHin[j] = h;            // Hend -> Hin in place (read-before-write)
        h = ap * h + he;
    }
}

__global__ __launch_bounds__(256)
void scan_pass3(const float* __restrict__ delta, const float* __restrict__ xz,
                const float* __restrict__ convw, const float* __restrict__ convb,
                const float* __restrict__ xdbl, const float* __restrict__ A_log,
                const float* __restrict__ D_skip, const float* __restrict__ Hin,
                _Float16* __restrict__ ygh)
{
    int gid = blockIdx.x * 256 + threadIdx.x;   // over B*CHUNKS*D*2
    if (gid >= BATCH * CHUNKS * D_INNER * 2) return;
    int lane = gid & 63;
    int wv   = gid >> 6;
    int dsub = lane & 31, nh = lane >> 5;
    int dblk = wv & 63;
    int c    = (wv >> 6) & (CHUNKS - 1);
    int b    = wv >> (6 + LOG2C);
    int d    = dblk * 32 + dsub;

    float An[8];
    {
        const float4* a4 = (const float4*)(A_log + d * 16 + nh * 8);
        #pragma unroll
        for (int q = 0; q < 2; ++q) {
            float4 v = a4[q];
            An[q * 4 + 0] = -__expf(v.x);
            An[q * 4 + 1] = -__expf(v.y);
            An[q * 4 + 2] = -__expf(v.z);
            An[q * 4 + 3] = -__expf(v.w);
        }
    }
    float4 cw = *(const float4*)(convw + (size_t)d * 4);
    float  cb = convb[d];
    float  Dd = D_skip[d];

    float h[8];
    {
        size_t off = ((((size_t)b * CHUNKS + c) * D_INNER) + d) * 16 + nh * 8;
        float4 v0 = *(const float4*)(Hin + off);
        float4 v1 = *(const float4*)(Hin + off + 4);
        h[0] = v0.x; h[1] = v0.y; h[2] = v0.z; h[3] = v0.w;
        h[4] = v1.x; h[5] = v1.y; h[6] = v1.z; h[7] = v1.w;
    }

    const float* dp = delta + ((size_t)b * SEQ + c * LC) * D_INNER + d;
    const float* xp = xz    + ((size_t)b * SEQ + c * LC) * 4096 + d;
    const float* rp = xp + D_INNER;
    const float* xb = xdbl  + ((size_t)b * SEQ + c * LC) * 96 + DT_RANK + nh * 8;
    _Float16*    yp = ygh   + ((size_t)b * SEQ + c * LC) * 2048 + d;

    float xw1 = 0.f, xw2 = 0.f, xw3 = 0.f;
    if (c > 0) {
        xw1 = xp[-4096];
        xw2 = xp[-2 * 4096];
        xw3 = xp[-3 * 4096];
    }

    float  dt = dp[0], x0 = xp[0], res = rp[0];
    float4 Bq0 = *(const float4*)(xb);
    float4 Bq1 = *(const float4*)(xb + 4);
    float4 Cq0 = *(const float4*)(xb + 16);
    float4 Cq1 = *(const float4*)(xb + 20);

    for (int l = 0; l < LC; ++l) {
        float dt_n, x0n, res_n;
        float4 B0n, B1n, C0n, C1n;
        if (l + 1 < LC) {
            dt_n  = dp[(size_t)(l + 1) * D_INNER];
            x0n   = xp[(size_t)(l + 1) * 4096];
            res_n = rp[(size_t)(l + 1) * 4096];
            B0n = *(const float4*)(xb + (l + 1) * 96);
            B1n = *(const float4*)(xb + (l + 1) * 96 + 4);
            C0n = *(const float4*)(xb + (l + 1) * 96 + 16);
            C1n = *(const float4*)(xb + (l + 1) * 96 + 20);
        }

        float ut = siluf(cb + cw.x * xw3 + cw.y * xw2 + cw.z * xw1 + cw.w * x0);
        float Bv[8] = { Bq0.x, Bq0.y, Bq0.z, Bq0.w, Bq1.x, Bq1.y, Bq1.z, Bq1.w };
        float Cv[8] = { Cq0.x, Cq0.y, Cq0.z, Cq0.w, Cq1.x, Cq1.y, Cq1.z, Cq1.w };
        float dtu = dt * ut;
        float y = 0.f;
        #pragma unroll
        for (int n = 0; n < 8; ++n) {
            float da = __expf(dt * An[n]);
            h[n] = fmaf(da, h[n], dtu * Bv[n]);
            y = fmaf(h[n], Cv[n], y);
        }
        y += __shfl_xor(y, 32, 64);
        if (nh == 0)
            yp[(size_t)l * 2048] = (_Float16)((y + ut * Dd) * siluf(res));

        xw3 = xw2; xw2 = xw1; xw1 = x0; x0 = x0n;
        dt = dt_n; res = res_n;
        Bq0 = B0n; Bq1 = B1n; Cq0 = C0n; Cq1 = C1n;
    }
}

// ---------------------------------------------------------------------------
extern "C" void kernel_launch(void* const* d_in, const int* in_sizes, int n_in,
                              void* d_out, int out_size, void* d_ws, size_t ws_size,
                              hipStream_t stream)
{
    const float* H      = (const float*)d_in[0];
    const float* Win    = (const float*)d_in[1];
    const float* convw  = (const float*)d_in[2];
    const float* convb  = (const float*)d_in[3];
    const float* xprojw = (const float*)d_in[4];
    const float* dtw    = (const float*)d_in[5];
    const float* dtb    = (const float*)d_in[6];
    const float* Alog   = (const float*)d_in[7];
    const float* Dskip  = (const float*)d_in[8];
    const float* Wout   = (const float*)d_in[9];
    float* out = (float*)d_out;

    float* ws    = (float*)d_ws;
    float* xz    = ws;                                   // [NTOK,4096] 32MB
    float* slotB = xz   + (size_t)NTOK * 4096;           // 16MB (Woutp + ygh)
    float* xdbl  = slotB + (size_t)NTOK * 2048;          // 0.75MB
    float* delta = xdbl + (size_t)NTOK * 96;             // 16MB
    float* Aprod = delta + (size_t)NTOK * 2048;          // 8MB
    float* Hend  = Aprod + (size_t)BATCH * CHUNKS * D_INNER * 16;  // 8MB

    // aliases (lifetime-disjoint):
    _Float16* Hh    = (_Float16*)delta;                  // dead after GEMM1
    _Float16* Winp  = (_Float16*)delta + 2 * 1024 * 1024;// dead after GEMM1
    float*    part  = delta;                             // GEMM2 partials
    float*    part4 = delta;                             // GEMM4 partials (16MB)
    _Float16* Woutp = (_Float16*)slotB;                  // 4MB
    _Float16* ygh   = (_Float16*)slotB + 2 * 1024 * 1024;// 8MB, ld 2048

    dim3 blk(256);

    // 0) prep: Hh = fp16(H); Winp = pack(Win); Woutp = pack(Wout)
    prep_kernel<<<5120, blk, 0, stream>>>(H, Win, Wout, Hh, Winp, Woutp);

    // 1) xz = H @ Win   (MFMA fp16; 1024 wg)
    gemm_f16_mfma<<<dim3((4096 / 64) * (NTOK / 128), 1, 1), blk, 0, stream>>>(
        Hh, Winp, xz, NTOK, 2 * D_INNER, D_MODEL, D_MODEL, 2 * D_INNER);

    // 2) x_dbl = silu(conv(x)+cb) @ x_proj_w  — fused conv, split-K z=16
    gemm2_conv_splitk<<<dim3(2, NTOK / 64, 16), blk, 0, stream>>>(
        xz, convw, convb, xprojw, part);
    reduce_splitk<<<(NTOK * 96 + 255) / 256, blk, 0, stream>>>(
        part, xdbl, NTOK * 96, 16);

    // 3) delta = softplus(x_dbl[:, :64] @ dt_proj_w + dt_proj_b)
    gemm_f32<true, true><<<dim3(D_INNER / 64, NTOK / 64), blk, 0, stream>>>(
        xdbl, dtw, dtb, delta, NTOK, D_INNER, DT_RANK, 96, D_INNER, D_INNER);

    // 4) chunk-parallel scan
    {
        int nthr2 = BATCH * CHUNKS * D_INNER * 2;        // 262,144
        scan_pass1<<<nthr2 / 256, blk, 0, stream>>>(delta, xz, convw, convb,
                                                    xdbl, Alog, Aprod, Hend);
        scan_pass2<<<(BATCH * D_INNER * 16) / 256, blk, 0, stream>>>(Aprod, Hend);
        scan_pass3<<<nthr2 / 256, blk, 0, stream>>>(delta, xz, convw, convb,
                                                    xdbl, Alog, Dskip,
                                                    Hend /*Hin*/, ygh);
    }

    // 5) out = yg @ Wout   (MFMA fp16; split-K=2)
    gemm_f16_mfma<<<dim3((1024 / 64) * (NTOK / 128), 1, 2), blk, 0, stream>>>(
        ygh, Woutp, part4, NTOK, D_MODEL, D_INNER, D_INNER, D_MODEL);
    reduce_splitk<<<(NTOK * D_MODEL) / 256, blk, 0, stream>>>(
        part4, out, NTOK * D_MODEL, 2);
}